// Round 1
// baseline (259.114 us; speedup 1.0000x reference)
//
#include <hip/hip_runtime.h>
#include <math.h>

// Problem constants
constexpr int B_ = 4;
constexpr int N_ = 2048;
constexpr int D_ = 128;
constexpr int H_ = 4;
constexpr int E_ = 32768;
constexpr int W_ = 8;
constexpr int OUT_ = 128;

// ---------------------------------------------------------------------------
// Kernel 1: Q/K/V GEMMs.  Out[n,e] = sum_d X[n,d]*W[e,d] + bias[e]
// grid = (N/32, B*H*3), block = 256.  32 rows x 128 cols per block,
// K-tiles of 32, 4x4 register blocking, W staged transposed in LDS.
// ---------------------------------------------------------------------------
__global__ __launch_bounds__(256) void qkv_gemm(
    const float* __restrict__ X,
    const float* __restrict__ Wq, const float* __restrict__ bq,
    const float* __restrict__ Wk, const float* __restrict__ bk,
    const float* __restrict__ Wv, const float* __restrict__ bv,
    float* __restrict__ Qo, float* __restrict__ Ko, float* __restrict__ Vo)
{
    const int g  = blockIdx.y;
    const int t3 = g % 3;
    const int bh = g / 3;
    const int b  = bh / H_;
    const int h  = bh % H_;
    const float* Wm; const float* bias; float* Out;
    if (t3 == 0)      { Wm = Wq; bias = bq; Out = Qo; }
    else if (t3 == 1) { Wm = Wk; bias = bk; Out = Ko; }
    else              { Wm = Wv; bias = bv; Out = Vo; }
    Wm  += (size_t)h * D_ * D_;
    bias += h * D_;
    float*       Ob = Out + (size_t)bh * N_ * D_ + (size_t)blockIdx.x * 32 * D_;
    const float* Xb = X   + (size_t)b  * N_ * D_ + (size_t)blockIdx.x * 32 * D_;

    __shared__ float Xs[32][36];   // [kk][row], padded for 16B-aligned float4 rows
    __shared__ float Ws[32][128];  // [kk][col]
    const int t  = threadIdx.x;
    const int tc = t & 31, tr = t >> 5;
    const int c0 = tc * 4, r0 = tr * 4;
    float acc[4][4] = {};

    for (int k0 = 0; k0 < D_; k0 += 32) {
        #pragma unroll
        for (int l = 0; l < 4; ++l) {                 // stage X tile (transposed)
            int lin = t + l * 256;
            int r = lin >> 5, kk = lin & 31;
            Xs[kk][r] = Xb[r * D_ + k0 + kk];
        }
        #pragma unroll
        for (int l = 0; l < 4; ++l) {                 // stage W tile (transposed)
            int lin = t + l * 256;
            int c = lin >> 3, k4 = lin & 7;
            float4 w = *(const float4*)&Wm[(size_t)c * D_ + k0 + k4 * 4];
            Ws[k4*4+0][c] = w.x; Ws[k4*4+1][c] = w.y;
            Ws[k4*4+2][c] = w.z; Ws[k4*4+3][c] = w.w;
        }
        __syncthreads();
        #pragma unroll
        for (int dd = 0; dd < 32; ++dd) {
            float4 xv = *(const float4*)&Xs[dd][r0];
            float4 wv = *(const float4*)&Ws[dd][c0];
            float xa[4] = {xv.x, xv.y, xv.z, xv.w};
            float wa[4] = {wv.x, wv.y, wv.z, wv.w};
            #pragma unroll
            for (int i2 = 0; i2 < 4; ++i2)
                #pragma unroll
                for (int j2 = 0; j2 < 4; ++j2)
                    acc[i2][j2] = fmaf(xa[i2], wa[j2], acc[i2][j2]);
        }
        __syncthreads();
    }
    float4 bb = *(const float4*)&bias[c0];
    float ba[4] = {bb.x, bb.y, bb.z, bb.w};
    #pragma unroll
    for (int i2 = 0; i2 < 4; ++i2) {
        float4 o;
        o.x = acc[i2][0] + ba[0]; o.y = acc[i2][1] + ba[1];
        o.z = acc[i2][2] + ba[2]; o.w = acc[i2][3] + ba[3];
        *(float4*)&Ob[(size_t)(r0 + i2) * D_ + c0] = o;
    }
}

// ---------------------------------------------------------------------------
// Kernel 2: Vsum[b,h,d] = sum_n V[b,h,n,d].  grid = (B*H, 8), block = 128.
// ---------------------------------------------------------------------------
__global__ __launch_bounds__(128) void vsum_kernel(const float* __restrict__ V,
                                                   float* __restrict__ vsum)
{
    const int bh = blockIdx.x;
    const int chunk = blockIdx.y;
    const int d = threadIdx.x;
    const int CH = N_ / 8;
    const float* Vb = V + (size_t)bh * N_ * D_;
    float s = 0.f;
    const int n0 = chunk * CH;
    for (int n = n0; n < n0 + CH; ++n) s += Vb[(size_t)n * D_ + d];
    atomicAdd(&vsum[bh * D_ + d], s);
}

// ---------------------------------------------------------------------------
// Kernel 3: per-edge exp values + row counts.  One wave per edge.
// grid = B*E/4, block = 256 (4 waves).
// ---------------------------------------------------------------------------
__global__ __launch_bounds__(256) void edge_kernel(
    const float* __restrict__ Q, const float* __restrict__ Km,
    const int* __restrict__ nidx, const float* __restrict__ attr,
    float* __restrict__ eexp, int* __restrict__ row_count)
{
    const int wave = threadIdx.x >> 6;
    const int lane = threadIdx.x & 63;
    const int eg = blockIdx.x * 4 + wave;        // 0 .. B*E-1
    const int b = eg / E_;
    const int e = eg % E_;
    const int i = nidx[b * 2 * E_ + e];
    const int j = nidx[b * 2 * E_ + E_ + e];

    float a = (lane < W_) ? attr[((size_t)b * E_ + e) * W_ + lane] : 0.f;
    #pragma unroll
    for (int off = 32; off; off >>= 1) a += __shfl_xor(a, off);
    const float wsum = a;
    const float rs = 1.0f / sqrtf((float)N_);

    #pragma unroll
    for (int h = 0; h < H_; ++h) {
        const float* qr = Q  + (((size_t)(b * H_ + h)) * N_ + i) * D_;
        const float* kr = Km + (((size_t)(b * H_ + h)) * N_ + j) * D_;
        float p = qr[lane] * kr[lane] + qr[lane + 64] * kr[lane + 64];
        #pragma unroll
        for (int off = 32; off; off >>= 1) p += __shfl_xor(p, off);
        if (lane == 0)
            eexp[((size_t)b * E_ + e) * H_ + h] = expf(p * rs * wsum);
    }
    if (lane == 0) atomicAdd(&row_count[b * N_ + i], 1);
}

// ---------------------------------------------------------------------------
// Kernel 4: exclusive scan over B*N row counts (single block).
// ---------------------------------------------------------------------------
__global__ __launch_bounds__(256) void scan_kernel(
    const int* __restrict__ cnt, int* __restrict__ start, int* __restrict__ cursor)
{
    __shared__ int s[256];
    __shared__ int carry;
    const int t = threadIdx.x;
    if (t == 0) carry = 0;
    __syncthreads();
    for (int base = 0; base < B_ * N_; base += 256) {
        int v = cnt[base + t];
        s[t] = v;
        __syncthreads();
        #pragma unroll
        for (int off = 1; off < 256; off <<= 1) {
            int add = (t >= off) ? s[t - off] : 0;
            __syncthreads();
            s[t] += add;
            __syncthreads();
        }
        int incl = s[t];
        int excl = carry + incl - v;
        start[base + t]  = excl;
        cursor[base + t] = excl;
        __syncthreads();
        if (t == 255) carry += incl;
        __syncthreads();
    }
}

// ---------------------------------------------------------------------------
// Kernel 5: scatter edge ids into CSR buckets.
// ---------------------------------------------------------------------------
__global__ __launch_bounds__(256) void scatter_kernel(
    const int* __restrict__ nidx, int* __restrict__ cursor, int* __restrict__ row_edges)
{
    const int eg = blockIdx.x * 256 + threadIdx.x;   // 0..B*E-1
    const int b = eg / E_;
    const int e = eg % E_;
    const int i = nidx[b * 2 * E_ + e];
    const int pos = atomicAdd(&cursor[b * N_ + i], 1);
    row_edges[pos] = e;
}

// ---------------------------------------------------------------------------
// Kernel 6: per-row sparse softmax+PV.  block = 256 (wave w = head w),
// grid = (N, B).  Exact last-e-wins dedup for duplicate (i,j).
// ---------------------------------------------------------------------------
constexpr int MAXL = 1024;
__global__ __launch_bounds__(256) void row_kernel(
    const float* __restrict__ V, const float* __restrict__ vsum,
    const float* __restrict__ eexp, const int* __restrict__ nidx,
    const int* __restrict__ row_start, const int* __restrict__ row_count,
    const int* __restrict__ row_edges, float* __restrict__ O)
{
    const int row = blockIdx.x;
    const int b   = blockIdx.y;
    const int t = threadIdx.x;
    const int wave = t >> 6, lane = t & 63;
    const int base = row_start[b * N_ + row];
    int cnt = row_count[b * N_ + row];
    if (cnt > MAXL) cnt = MAXL;   // never triggers for this dataset (Poisson(16))

    __shared__ int lj[MAXL];
    __shared__ int le[MAXL];
    __shared__ unsigned char lw[MAXL];
    for (int p = t; p < cnt; p += 256) {
        int e = row_edges[base + p];
        le[p] = e;
        lj[p] = nidx[b * 2 * E_ + E_ + e];
    }
    __syncthreads();
    for (int p = t; p < cnt; p += 256) {   // last-e-wins dedup per (i,j)
        int j = lj[p], e = le[p];
        bool w = true;
        for (int q2 = 0; q2 < cnt; ++q2)
            if (lj[q2] == j && le[q2] > e) { w = false; break; }
        lw[p] = w ? 1 : 0;
    }
    __syncthreads();

    const int h = wave;
    const float* Vh = V + (size_t)(b * H_ + h) * N_ * D_;
    float acc0 = 0.f, acc1 = 0.f, dsum = 0.f;
    for (int p = 0; p < cnt; ++p) {
        if (!lw[p]) continue;
        float x = eexp[((size_t)b * E_ + le[p]) * H_ + h] - 1.f;
        dsum += x;
        const float* vr = Vh + (size_t)lj[p] * D_;
        acc0 = fmaf(x, vr[lane],      acc0);
        acc1 = fmaf(x, vr[lane + 64], acc1);
    }
    const float denom = (float)N_ + dsum;
    const float inv = 1.0f / denom;
    const float* vs = vsum + (b * H_ + h) * D_;
    float* o = O + ((size_t)b * N_ + row) * (H_ * D_) + h * D_;
    o[lane]      = (vs[lane]      + acc0) * inv;
    o[lane + 64] = (vs[lane + 64] + acc1) * inv;
}

// ---------------------------------------------------------------------------
// Kernel 7: output projection.  final[m,o] = sum_k O[m,k]*Wout[o,k] + bout[o]
// grid = B*N/32, block = 256.  K = 512, 128 output cols.
// ---------------------------------------------------------------------------
__global__ __launch_bounds__(256) void out_gemm(
    const float* __restrict__ Xo, const float* __restrict__ Wo,
    const float* __restrict__ bo, float* __restrict__ Out)
{
    constexpr int KD = H_ * D_;  // 512
    const float* Xb = Xo + (size_t)blockIdx.x * 32 * KD;
    float*       Ob = Out + (size_t)blockIdx.x * 32 * OUT_;

    __shared__ float Xs[32][36];
    __shared__ float Ws[32][128];
    const int t  = threadIdx.x;
    const int tc = t & 31, tr = t >> 5;
    const int c0 = tc * 4, r0 = tr * 4;
    float acc[4][4] = {};

    for (int k0 = 0; k0 < KD; k0 += 32) {
        #pragma unroll
        for (int l = 0; l < 4; ++l) {
            int lin = t + l * 256;
            int r = lin >> 5, kk = lin & 31;
            Xs[kk][r] = Xb[r * KD + k0 + kk];
        }
        #pragma unroll
        for (int l = 0; l < 4; ++l) {
            int lin = t + l * 256;
            int c = lin >> 3, k4 = lin & 7;
            float4 w = *(const float4*)&Wo[(size_t)c * KD + k0 + k4 * 4];
            Ws[k4*4+0][c] = w.x; Ws[k4*4+1][c] = w.y;
            Ws[k4*4+2][c] = w.z; Ws[k4*4+3][c] = w.w;
        }
        __syncthreads();
        #pragma unroll
        for (int dd = 0; dd < 32; ++dd) {
            float4 xv = *(const float4*)&Xs[dd][r0];
            float4 wv = *(const float4*)&Ws[dd][c0];
            float xa[4] = {xv.x, xv.y, xv.z, xv.w};
            float wa[4] = {wv.x, wv.y, wv.z, wv.w};
            #pragma unroll
            for (int i2 = 0; i2 < 4; ++i2)
                #pragma unroll
                for (int j2 = 0; j2 < 4; ++j2)
                    acc[i2][j2] = fmaf(xa[i2], wa[j2], acc[i2][j2]);
        }
        __syncthreads();
    }
    float4 bb = *(const float4*)&bo[c0];
    float ba[4] = {bb.x, bb.y, bb.z, bb.w};
    #pragma unroll
    for (int i2 = 0; i2 < 4; ++i2) {
        float4 o;
        o.x = acc[i2][0] + ba[0]; o.y = acc[i2][1] + ba[1];
        o.z = acc[i2][2] + ba[2]; o.w = acc[i2][3] + ba[3];
        *(float4*)&Ob[(size_t)(r0 + i2) * OUT_ + c0] = o;
    }
}

// ---------------------------------------------------------------------------
extern "C" void kernel_launch(void* const* d_in, const int* in_sizes, int n_in,
                              void* d_out, int out_size, void* d_ws, size_t ws_size,
                              hipStream_t stream)
{
    const float* x     = (const float*)d_in[0];
    const int*   nidx  = (const int*)  d_in[1];
    const float* attr  = (const float*)d_in[2];
    const float* wq_w  = (const float*)d_in[3];
    const float* wq_b  = (const float*)d_in[4];
    const float* wk_w  = (const float*)d_in[5];
    const float* wk_b  = (const float*)d_in[6];
    const float* wv_w  = (const float*)d_in[7];
    const float* wv_b  = (const float*)d_in[8];
    const float* out_w = (const float*)d_in[9];
    const float* out_b = (const float*)d_in[10];
    float* out = (float*)d_out;

    char* ws = (char*)d_ws;
    size_t off = 0;
    auto alloc = [&](size_t bytes) -> char* {
        char* p = ws + off;
        off += (bytes + 255) & ~(size_t)255;
        return p;
    };
    float* Q = (float*)alloc((size_t)B_ * H_ * N_ * D_ * 4);  // reused as O later
    float* K = (float*)alloc((size_t)B_ * H_ * N_ * D_ * 4);
    float* V = (float*)alloc((size_t)B_ * H_ * N_ * D_ * 4);
    float* eexp = (float*)alloc((size_t)B_ * E_ * H_ * 4);
    float* vsum = (float*)alloc((size_t)B_ * H_ * D_ * 4);
    int* row_count = (int*)alloc((size_t)B_ * N_ * 4);
    int* row_start = (int*)alloc((size_t)B_ * N_ * 4);
    int* row_cur   = (int*)alloc((size_t)B_ * N_ * 4);
    int* row_edges = (int*)alloc((size_t)B_ * E_ * 4);
    float* O = Q;  // Q dead after edge_kernel; alias

    hipMemsetAsync(row_count, 0, (size_t)B_ * N_ * 4, stream);
    hipMemsetAsync(vsum, 0, (size_t)B_ * H_ * D_ * 4, stream);

    qkv_gemm<<<dim3(N_ / 32, B_ * H_ * 3), 256, 0, stream>>>(
        x, wq_w, wq_b, wk_w, wk_b, wv_w, wv_b, Q, K, V);
    vsum_kernel<<<dim3(B_ * H_, 8), 128, 0, stream>>>(V, vsum);
    edge_kernel<<<(B_ * E_) / 4, 256, 0, stream>>>(Q, K, nidx, attr, eexp, row_count);
    scan_kernel<<<1, 256, 0, stream>>>(row_count, row_start, row_cur);
    scatter_kernel<<<(B_ * E_) / 256, 256, 0, stream>>>(nidx, row_cur, row_edges);
    row_kernel<<<dim3(N_, B_), 256, 0, stream>>>(
        V, vsum, eexp, nidx, row_start, row_count, row_edges, O);
    out_gemm<<<(B_ * N_) / 32, 256, 0, stream>>>(O, out_w, out_b, out);
}

// Round 2
// 188.113 us; speedup vs baseline: 1.3774x; 1.3774x over previous
//
#include <hip/hip_runtime.h>
#include <math.h>

// Problem constants
constexpr int B_ = 4;
constexpr int N_ = 2048;
constexpr int D_ = 128;
constexpr int H_ = 4;
constexpr int E_ = 32768;
constexpr int W_ = 8;
constexpr int OUT_ = 128;
constexpr int HD_ = H_ * D_;   // 512
constexpr int CAP = 64;        // max edges per row bucket (Poisson(16); P(>=64) ~ 1e-40)

// ---------------------------------------------------------------------------
// Kernel 1: Q/K/V GEMMs.  Out[(b,n),(h,d)] interleaved layout [b][n][h][d].
// grid = (N/32, B*H*3), block = 256.  32 rows x 128 cols per block.
// ---------------------------------------------------------------------------
__global__ __launch_bounds__(256) void qkv_gemm(
    const float* __restrict__ X,
    const float* __restrict__ Wq, const float* __restrict__ bq,
    const float* __restrict__ Wk, const float* __restrict__ bk,
    const float* __restrict__ Wv, const float* __restrict__ bv,
    float* __restrict__ Qo, float* __restrict__ Ko, float* __restrict__ Vo)
{
    const int g  = blockIdx.y;
    const int t3 = g % 3;
    const int bh = g / 3;
    const int b  = bh / H_;
    const int h  = bh % H_;
    const float* Wm; const float* bias; float* Out;
    if (t3 == 0)      { Wm = Wq; bias = bq; Out = Qo; }
    else if (t3 == 1) { Wm = Wk; bias = bk; Out = Ko; }
    else              { Wm = Wv; bias = bv; Out = Vo; }
    Wm  += (size_t)h * D_ * D_;
    bias += h * D_;
    // interleaved output: row stride HD_, head offset h*D_
    float*       Ob = Out + ((size_t)b * N_ + (size_t)blockIdx.x * 32) * HD_ + h * D_;
    const float* Xb = X   + ((size_t)b * N_ + (size_t)blockIdx.x * 32) * D_;

    __shared__ float Xs[32][36];   // [kk][row]
    __shared__ float Ws[32][128];  // [kk][col]
    const int t  = threadIdx.x;
    const int tc = t & 31, tr = t >> 5;
    const int c0 = tc * 4, r0 = tr * 4;
    float acc[4][4] = {};

    for (int k0 = 0; k0 < D_; k0 += 32) {
        #pragma unroll
        for (int l = 0; l < 4; ++l) {                 // stage X tile (transposed)
            int lin = t + l * 256;
            int r = lin >> 5, kk = lin & 31;
            Xs[kk][r] = Xb[r * D_ + k0 + kk];
        }
        #pragma unroll
        for (int l = 0; l < 4; ++l) {                 // stage W tile (transposed)
            int lin = t + l * 256;
            int c = lin >> 3, k4 = lin & 7;
            float4 w = *(const float4*)&Wm[(size_t)c * D_ + k0 + k4 * 4];
            Ws[k4*4+0][c] = w.x; Ws[k4*4+1][c] = w.y;
            Ws[k4*4+2][c] = w.z; Ws[k4*4+3][c] = w.w;
        }
        __syncthreads();
        #pragma unroll
        for (int dd = 0; dd < 32; ++dd) {
            float4 xv = *(const float4*)&Xs[dd][r0];
            float4 wv = *(const float4*)&Ws[dd][c0];
            float xa[4] = {xv.x, xv.y, xv.z, xv.w};
            float wa[4] = {wv.x, wv.y, wv.z, wv.w};
            #pragma unroll
            for (int i2 = 0; i2 < 4; ++i2)
                #pragma unroll
                for (int j2 = 0; j2 < 4; ++j2)
                    acc[i2][j2] = fmaf(xa[i2], wa[j2], acc[i2][j2]);
        }
        __syncthreads();
    }
    float4 bb = *(const float4*)&bias[c0];
    float ba[4] = {bb.x, bb.y, bb.z, bb.w};
    #pragma unroll
    for (int i2 = 0; i2 < 4; ++i2) {
        float4 o;
        o.x = acc[i2][0] + ba[0]; o.y = acc[i2][1] + ba[1];
        o.z = acc[i2][2] + ba[2]; o.w = acc[i2][3] + ba[3];
        *(float4*)&Ob[(size_t)(r0 + i2) * HD_ + c0] = o;
    }
}

// ---------------------------------------------------------------------------
// Kernel 2: Vsum[b,h,d] = sum_n V[b][n][h][d].  grid = (B*H, 8), block = 128.
// ---------------------------------------------------------------------------
__global__ __launch_bounds__(128) void vsum_kernel(const float* __restrict__ V,
                                                   float* __restrict__ vsum)
{
    const int bh = blockIdx.x;
    const int b = bh / H_, h = bh % H_;
    const int chunk = blockIdx.y;
    const int d = threadIdx.x;
    const int CH = N_ / 8;
    const float* Vb = V + (size_t)b * N_ * HD_ + h * D_;
    float s = 0.f;
    const int n0 = chunk * CH;
    for (int n = n0; n < n0 + CH; ++n) s += Vb[(size_t)n * HD_ + d];
    atomicAdd(&vsum[bh * D_ + d], s);
}

// ---------------------------------------------------------------------------
// Kernel 3: append edges to per-row buckets + precompute wsum.
// 8 edges per wave (coalesced attr read), grid = B*E/32, block = 256.
// Bucket entry: int2 { e | (j<<16), bitcast(wsum) }
// ---------------------------------------------------------------------------
__global__ __launch_bounds__(256) void append_kernel(
    const int* __restrict__ nidx, const float* __restrict__ attr,
    int* __restrict__ row_count, int2* __restrict__ row_edges)
{
    const int wave = threadIdx.x >> 6;
    const int lane = threadIdx.x & 63;
    const int gw = blockIdx.x * 4 + wave;      // global wave id
    const int e0g = gw * 8;                    // first global edge of this wave
    const int b = e0g / E_;
    const int e0 = e0g % E_;                   // 8 consecutive edges, same batch

    // wsum for 8 edges: 64 contiguous attr floats
    float a = attr[((size_t)b * E_ + e0) * W_ + lane];
    a += __shfl_xor(a, 1);
    a += __shfl_xor(a, 2);
    a += __shfl_xor(a, 4);                     // 8-lane groups each hold a full sum

    if ((lane & 7) == 0) {
        const int sub = lane >> 3;
        const int e = e0 + sub;
        const int i = nidx[b * 2 * E_ + e];
        const int j = nidx[b * 2 * E_ + E_ + e];
        const int pos = atomicAdd(&row_count[b * N_ + i], 1);
        if (pos < CAP)
            row_edges[(size_t)(b * N_ + i) * CAP + pos] =
                make_int2(e | (j << 16), __float_as_int(a));
    }
}

// ---------------------------------------------------------------------------
// Kernel 4: fused per-row scoring + sparse softmax + PV.
// grid = (N, B), block = 256 (4 waves).  Each block owns one (b,row):
//   - q row (all heads, 2KB) loaded once into registers per wave
//   - phase A: waves score edges p = w,w+4,... (16-lane group per head)
//   - dedup: exact last-e-wins (max-e among same j)
//   - phase B: wave h accumulates (exp-1)*v over winner edges
// O written in-place over Q (each block touches only its own row).
// ---------------------------------------------------------------------------
__global__ __launch_bounds__(256) void row_fused(
    const float* __restrict__ Q, const float* __restrict__ K,
    const float* __restrict__ V, const float* __restrict__ vsum,
    const int* __restrict__ row_count, const int2* __restrict__ row_edges,
    float* __restrict__ O)
{
    const int row = blockIdx.x;
    const int b   = blockIdx.y;
    const int t = threadIdx.x;
    const int wave = t >> 6, lane = t & 63;
    int cnt = row_count[b * N_ + row];
    if (cnt > CAP) cnt = CAP;

    __shared__ int   le[CAP];
    __shared__ int   lj[CAP];
    __shared__ float lws[CAP];
    __shared__ float sexp[CAP * H_];
    __shared__ unsigned char lw[CAP];

    if (t < cnt) {
        int2 v = row_edges[(size_t)(b * N_ + row) * CAP + t];
        le[t] = v.x & 0xFFFF;
        lj[t] = v.x >> 16;
        lws[t] = __int_as_float(v.y);
    }
    __syncthreads();
    if (t < cnt) {                       // last-e-wins dedup: winner = max e per j
        const int j = lj[t], e = le[t];
        bool w = true;
        for (int q2 = 0; q2 < cnt; ++q2)
            if (lj[q2] == j && le[q2] > e) { w = false; break; }
        lw[t] = w ? 1 : 0;
    }
    __syncthreads();

    // q row in registers: lane covers floats [lane*8, lane*8+8) => head lane>>4
    const float* qb = Q + ((size_t)b * N_ + row) * HD_;
    const float4 q0 = *(const float4*)(qb + lane * 8);
    const float4 q1 = *(const float4*)(qb + lane * 8 + 4);
    const float rs = 0.02209708691207961f;   // 1/sqrt(2048)

    // phase A: score edges
    for (int p = wave; p < cnt; p += 4) {
        if (!lw[p]) continue;
        const int j = lj[p];
        const float* kb = K + ((size_t)b * N_ + j) * HD_;
        const float4 k0 = *(const float4*)(kb + lane * 8);
        const float4 k1 = *(const float4*)(kb + lane * 8 + 4);
        float s = q0.x*k0.x + q0.y*k0.y + q0.z*k0.z + q0.w*k0.w
                + q1.x*k1.x + q1.y*k1.y + q1.z*k1.z + q1.w*k1.w;
        s += __shfl_xor(s, 1);
        s += __shfl_xor(s, 2);
        s += __shfl_xor(s, 4);
        s += __shfl_xor(s, 8);               // 16-lane group = one head
        if ((lane & 15) == 0)
            sexp[p * H_ + (lane >> 4)] = expf(s * rs * lws[p]);
    }
    __syncthreads();

    // phase B: per-head accumulation (wave = head)
    const int h = wave;
    const float* Vh = V + h * D_;
    float2 acc = make_float2(0.f, 0.f);
    float dsum = 0.f;
    for (int p = 0; p < cnt; ++p) {
        if (!lw[p]) continue;
        const float x = sexp[p * H_ + h] - 1.f;
        dsum += x;
        const float* vr = Vh + ((size_t)b * N_ + lj[p]) * HD_;
        const float2 vv = *(const float2*)(vr + lane * 2);
        acc.x = fmaf(x, vv.x, acc.x);
        acc.y = fmaf(x, vv.y, acc.y);
    }
    const float inv = 1.0f / ((float)N_ + dsum);
    const float2 vs = *(const float2*)(vsum + (b * H_ + h) * D_ + lane * 2);
    float* o = O + ((size_t)b * N_ + row) * HD_ + h * D_;
    *(float2*)(o + lane * 2) = make_float2((vs.x + acc.x) * inv,
                                           (vs.y + acc.y) * inv);
}

// ---------------------------------------------------------------------------
// Kernel 5: output projection.  final[m,o] = sum_k O[m,k]*Wout[o,k] + bout[o]
// grid = B*N/32, block = 256.  K = 512, 128 output cols.
// ---------------------------------------------------------------------------
__global__ __launch_bounds__(256) void out_gemm(
    const float* __restrict__ Xo, const float* __restrict__ Wo,
    const float* __restrict__ bo, float* __restrict__ Out)
{
    constexpr int KD = HD_;  // 512
    const float* Xb = Xo + (size_t)blockIdx.x * 32 * KD;
    float*       Ob = Out + (size_t)blockIdx.x * 32 * OUT_;

    __shared__ float Xs[32][36];
    __shared__ float Ws[32][128];
    const int t  = threadIdx.x;
    const int tc = t & 31, tr = t >> 5;
    const int c0 = tc * 4, r0 = tr * 4;
    float acc[4][4] = {};

    for (int k0 = 0; k0 < KD; k0 += 32) {
        #pragma unroll
        for (int l = 0; l < 4; ++l) {
            int lin = t + l * 256;
            int r = lin >> 5, kk = lin & 31;
            Xs[kk][r] = Xb[r * KD + k0 + kk];
        }
        #pragma unroll
        for (int l = 0; l < 4; ++l) {
            int lin = t + l * 256;
            int c = lin >> 3, k4 = lin & 7;
            float4 w = *(const float4*)&Wo[(size_t)c * KD + k0 + k4 * 4];
            Ws[k4*4+0][c] = w.x; Ws[k4*4+1][c] = w.y;
            Ws[k4*4+2][c] = w.z; Ws[k4*4+3][c] = w.w;
        }
        __syncthreads();
        #pragma unroll
        for (int dd = 0; dd < 32; ++dd) {
            float4 xv = *(const float4*)&Xs[dd][r0];
            float4 wv = *(const float4*)&Ws[dd][c0];
            float xa[4] = {xv.x, xv.y, xv.z, xv.w};
            float wa[4] = {wv.x, wv.y, wv.z, wv.w};
            #pragma unroll
            for (int i2 = 0; i2 < 4; ++i2)
                #pragma unroll
                for (int j2 = 0; j2 < 4; ++j2)
                    acc[i2][j2] = fmaf(xa[i2], wa[j2], acc[i2][j2]);
        }
        __syncthreads();
    }
    float4 bb = *(const float4*)&bo[c0];
    float ba[4] = {bb.x, bb.y, bb.z, bb.w};
    #pragma unroll
    for (int i2 = 0; i2 < 4; ++i2) {
        float4 o;
        o.x = acc[i2][0] + ba[0]; o.y = acc[i2][1] + ba[1];
        o.z = acc[i2][2] + ba[2]; o.w = acc[i2][3] + ba[3];
        *(float4*)&Ob[(size_t)(r0 + i2) * OUT_ + c0] = o;
    }
}

// ---------------------------------------------------------------------------
extern "C" void kernel_launch(void* const* d_in, const int* in_sizes, int n_in,
                              void* d_out, int out_size, void* d_ws, size_t ws_size,
                              hipStream_t stream)
{
    const float* x     = (const float*)d_in[0];
    const int*   nidx  = (const int*)  d_in[1];
    const float* attr  = (const float*)d_in[2];
    const float* wq_w  = (const float*)d_in[3];
    const float* wq_b  = (const float*)d_in[4];
    const float* wk_w  = (const float*)d_in[5];
    const float* wk_b  = (const float*)d_in[6];
    const float* wv_w  = (const float*)d_in[7];
    const float* wv_b  = (const float*)d_in[8];
    const float* out_w = (const float*)d_in[9];
    const float* out_b = (const float*)d_in[10];
    float* out = (float*)d_out;

    char* ws = (char*)d_ws;
    size_t off = 0;
    auto alloc = [&](size_t bytes) -> char* {
        char* p = ws + off;
        off += (bytes + 255) & ~(size_t)255;
        return p;
    };
    float* Q = (float*)alloc((size_t)B_ * N_ * HD_ * 4);  // also O (in-place per row)
    float* K = (float*)alloc((size_t)B_ * N_ * HD_ * 4);
    float* V = (float*)alloc((size_t)B_ * N_ * HD_ * 4);
    float* vsum = (float*)alloc((size_t)B_ * H_ * D_ * 4);
    int*  row_count = (int*)alloc((size_t)B_ * N_ * 4);
    int2* row_edges = (int2*)alloc((size_t)B_ * N_ * CAP * 8);

    hipMemsetAsync(row_count, 0, (size_t)B_ * N_ * 4, stream);
    hipMemsetAsync(vsum, 0, (size_t)B_ * H_ * D_ * 4, stream);

    qkv_gemm<<<dim3(N_ / 32, B_ * H_ * 3), 256, 0, stream>>>(
        x, wq_w, wq_b, wk_w, wk_b, wv_w, wv_b, Q, K, V);
    vsum_kernel<<<dim3(B_ * H_, 8), 128, 0, stream>>>(V, vsum);
    append_kernel<<<(B_ * E_) / 32, 256, 0, stream>>>(nidx, attr, row_count, row_edges);
    row_fused<<<dim3(N_, B_), 256, 0, stream>>>(Q, K, V, vsum, row_count, row_edges, Q);
    out_gemm<<<(B_ * N_) / 32, 256, 0, stream>>>(Q, out_w, out_b, out);
}

// Round 3
// 132.883 us; speedup vs baseline: 1.9499x; 1.4156x over previous
//
#include <hip/hip_runtime.h>
#include <hip/hip_bf16.h>
#include <math.h>

// Problem constants
constexpr int B_ = 4;
constexpr int N_ = 2048;
constexpr int D_ = 128;
constexpr int H_ = 4;
constexpr int E_ = 32768;
constexpr int W_ = 8;
constexpr int OUT_ = 128;
constexpr int HD_ = H_ * D_;    // 512
constexpr int C3_ = 3 * HD_;    // 1536 combined QKV cols
constexpr int CAP = 64;         // max edges per row bucket (Poisson(16))
constexpr int M_ = B_ * N_;     // 8192 rows

typedef __attribute__((ext_vector_type(8))) __bf16 bf16x8;
typedef __attribute__((ext_vector_type(4))) float f32x4;
typedef unsigned int uint32;
typedef unsigned short u16;

__device__ __forceinline__ u16 f2b(float f) {
    __hip_bfloat16 h = __float2bfloat16(f);
    return *(u16*)&h;
}
__device__ __forceinline__ float blo(uint32 u) { return __uint_as_float(u << 16); }
__device__ __forceinline__ float bhi(uint32 u) { return __uint_as_float(u & 0xffff0000u); }

// async 16B global->LDS copy (dest = wave-uniform base + lane*16)
__device__ __forceinline__ void g2l16(const void* g, void* l) {
    __builtin_amdgcn_global_load_lds(
        (const __attribute__((address_space(1))) unsigned int*)(uintptr_t)g,
        (__attribute__((address_space(3))) unsigned int*)(uintptr_t)l,
        16, 0, 0);
}

// ---------------------------------------------------------------------------
// cast_x: x f32 [8192][128] -> bf16, XOR-swizzled within each 256B row.
// 131072 threads, 8 elems each.
// ---------------------------------------------------------------------------
__global__ __launch_bounds__(256) void cast_x(const float* __restrict__ X,
                                              u16* __restrict__ Xbf)
{
    const int tid = blockIdx.x * 256 + threadIdx.x;
    const int row = tid >> 4, sub = tid & 15;
    const float4 f0 = *(const float4*)(X + (size_t)row * 128 + sub * 8);
    const float4 f1 = *(const float4*)(X + (size_t)row * 128 + sub * 8 + 4);
    union { u16 u[8]; uint4 v; } pk;
    pk.u[0]=f2b(f0.x); pk.u[1]=f2b(f0.y); pk.u[2]=f2b(f0.z); pk.u[3]=f2b(f0.w);
    pk.u[4]=f2b(f1.x); pk.u[5]=f2b(f1.y); pk.u[6]=f2b(f1.z); pk.u[7]=f2b(f1.w);
    const int ob = row * 256 + ((sub * 16) ^ ((row & 7) << 4));
    *(uint4*)((char*)Xbf + ob) = pk.v;
}

// ---------------------------------------------------------------------------
// cast_w: 12 weight matrices [128 e][128 d] -> Wbf [12][128][256B swz]; bias.
// grid = 12 blocks.
// ---------------------------------------------------------------------------
__global__ __launch_bounds__(256) void cast_w(
    const float* __restrict__ wq, const float* __restrict__ wk, const float* __restrict__ wv,
    const float* __restrict__ bq, const float* __restrict__ bk, const float* __restrict__ bv,
    u16* __restrict__ Wbf, float* __restrict__ biasf)
{
    const int g = blockIdx.x;
    const int t3 = g >> 2, h = g & 3;
    const float* Wsrc = (t3 == 0 ? wq : t3 == 1 ? wk : wv) + (size_t)h * 128 * 128;
    const float* Bsrc = (t3 == 0 ? bq : t3 == 1 ? bk : bv) + h * 128;
    for (int q = 0; q < 8; ++q) {
        const int idx = threadIdx.x + q * 256;   // 2048 chunks
        const int e = idx >> 4, sub = idx & 15;
        const float4 f0 = *(const float4*)(Wsrc + (size_t)e * 128 + sub * 8);
        const float4 f1 = *(const float4*)(Wsrc + (size_t)e * 128 + sub * 8 + 4);
        union { u16 u[8]; uint4 v; } pk;
        pk.u[0]=f2b(f0.x); pk.u[1]=f2b(f0.y); pk.u[2]=f2b(f0.z); pk.u[3]=f2b(f0.w);
        pk.u[4]=f2b(f1.x); pk.u[5]=f2b(f1.y); pk.u[6]=f2b(f1.z); pk.u[7]=f2b(f1.w);
        const int ob = g * 32768 + e * 256 + ((sub * 16) ^ ((e & 7) << 4));
        *(uint4*)((char*)Wbf + ob) = pk.v;
    }
    if (threadIdx.x < 128) biasf[g * 128 + threadIdx.x] = Bsrc[threadIdx.x];
}

// ---------------------------------------------------------------------------
// cast_ow: out_w f32 [128][512] -> bf16, swizzled per 256B k-chunk.
// ---------------------------------------------------------------------------
__global__ __launch_bounds__(256) void cast_ow(const float* __restrict__ OW,
                                               u16* __restrict__ OWbf)
{
    const int tid = blockIdx.x * 256 + threadIdx.x;  // 8192 chunks
    const int c = tid >> 6, sub = tid & 63;
    const float4 f0 = *(const float4*)(OW + (size_t)c * 512 + sub * 8);
    const float4 f1 = *(const float4*)(OW + (size_t)c * 512 + sub * 8 + 4);
    union { u16 u[8]; uint4 v; } pk;
    pk.u[0]=f2b(f0.x); pk.u[1]=f2b(f0.y); pk.u[2]=f2b(f0.z); pk.u[3]=f2b(f0.w);
    pk.u[4]=f2b(f1.x); pk.u[5]=f2b(f1.y); pk.u[6]=f2b(f1.z); pk.u[7]=f2b(f1.w);
    const int ob = c * 1024 + ((sub * 16) ^ ((c & 7) << 4));
    *(uint4*)((char*)OWbf + ob) = pk.v;
}

// ---------------------------------------------------------------------------
// qkv_mfma: QKV[8192][1536] bf16 = Xbf[8192][128] x Wbf[12 x 128][128]^T + bias
// grid = 768 = 64 row-blocks x 12 col-blocks.  Tile 128x128, K=128 (no K loop).
// 4 waves (2x2), wave tile 64x64, mfma_f32_16x16x32_bf16.
// ---------------------------------------------------------------------------
__global__ __launch_bounds__(256) void qkv_mfma(
    const u16* __restrict__ Xbf, const u16* __restrict__ Wbf,
    const float* __restrict__ biasf, u16* __restrict__ QKV)
{
    __shared__ u16 As[128 * 128];
    __shared__ u16 Bs[128 * 128];
    const int rb = blockIdx.x & 63;
    const int g  = blockIdx.x >> 6;
    const int t = threadIdx.x;
    const int lane = t & 63, wave = t >> 6;
    const int wm = wave >> 1, wn = wave & 1;
    const int l15 = lane & 15, l4 = lane >> 4;

    // stage A + B tiles (32KB each, linear copy of pre-swizzled source)
    const char* Asrc = (const char*)(Xbf + (size_t)rb * 128 * 128);
    const char* Bsrc = (const char*)(Wbf + (size_t)g  * 128 * 128);
    #pragma unroll
    for (int q = 0; q < 8; ++q) {
        const int o = t * 16 + q * 4096;
        g2l16(Asrc + o, (char*)As + o);
        g2l16(Bsrc + o, (char*)Bs + o);
    }
    __syncthreads();

    f32x4 acc[4][4];
    #pragma unroll
    for (int i = 0; i < 4; ++i)
        #pragma unroll
        for (int j = 0; j < 4; ++j) acc[i][j] = (f32x4){0.f, 0.f, 0.f, 0.f};

    #pragma unroll
    for (int ks = 0; ks < 4; ++ks) {
        const int kb = ks * 64 + l4 * 16;
        bf16x8 a[4], bb[4];
        #pragma unroll
        for (int fm = 0; fm < 4; ++fm) {
            const int row = wm * 64 + fm * 16 + l15;
            a[fm] = *(const bf16x8*)((const char*)As + row * 256 + (kb ^ ((row & 7) << 4)));
        }
        #pragma unroll
        for (int fn = 0; fn < 4; ++fn) {
            const int col = wn * 64 + fn * 16 + l15;
            bb[fn] = *(const bf16x8*)((const char*)Bs + col * 256 + (kb ^ ((col & 7) << 4)));
        }
        #pragma unroll
        for (int fm = 0; fm < 4; ++fm)
            #pragma unroll
            for (int fn = 0; fn < 4; ++fn)
                acc[fm][fn] = __builtin_amdgcn_mfma_f32_16x16x32_bf16(
                    a[fm], bb[fn], acc[fm][fn], 0, 0, 0);
    }

    // epilogue: D[row][col]: col = lane&15 (+frag), row = (lane>>4)*4 + reg
    #pragma unroll
    for (int fm = 0; fm < 4; ++fm)
        #pragma unroll
        for (int fn = 0; fn < 4; ++fn) {
            const int col = wn * 64 + fn * 16 + l15;
            const float bv = biasf[g * 128 + col];
            const int gcol = g * 128 + col;
            #pragma unroll
            for (int r = 0; r < 4; ++r) {
                const int row = rb * 128 + wm * 64 + fm * 16 + l4 * 4 + r;
                QKV[(size_t)row * C3_ + gcol] = f2b(acc[fm][fn][r] + bv);
            }
        }
}

// ---------------------------------------------------------------------------
// vsum_kernel: Vsum[b,h,d] = sum_n V (bf16 read, f32 accum).
// V at QKV col offset 1024 + h*128.  grid = (B*H, 8), block = 128.
// ---------------------------------------------------------------------------
__global__ __launch_bounds__(128) void vsum_kernel(const u16* __restrict__ QKV,
                                                   float* __restrict__ vsum)
{
    const int bh = blockIdx.x;
    const int b = bh / H_, h = bh % H_;
    const int chunk = blockIdx.y;
    const int d = threadIdx.x;
    const int CH = N_ / 8;
    float s = 0.f;
    const int n0 = chunk * CH;
    for (int n = n0; n < n0 + CH; ++n) {
        const u16 u = QKV[(size_t)(b * N_ + n) * C3_ + 1024 + h * 128 + d];
        s += __uint_as_float((uint32)u << 16);
    }
    atomicAdd(&vsum[bh * 128 + d], s);
}

// ---------------------------------------------------------------------------
// append_kernel: edges -> per-row buckets + wsum.  8 edges/wave.
// ---------------------------------------------------------------------------
__global__ __launch_bounds__(256) void append_kernel(
    const int* __restrict__ nidx, const float* __restrict__ attr,
    int* __restrict__ row_count, int2* __restrict__ row_edges)
{
    const int wave = threadIdx.x >> 6;
    const int lane = threadIdx.x & 63;
    const int gw = blockIdx.x * 4 + wave;
    const int e0g = gw * 8;
    const int b = e0g / E_;
    const int e0 = e0g % E_;

    float a = attr[((size_t)b * E_ + e0) * W_ + lane];
    a += __shfl_xor(a, 1);
    a += __shfl_xor(a, 2);
    a += __shfl_xor(a, 4);

    if ((lane & 7) == 0) {
        const int sub = lane >> 3;
        const int e = e0 + sub;
        const int i = nidx[b * 2 * E_ + e];
        const int j = nidx[b * 2 * E_ + E_ + e];
        const int pos = atomicAdd(&row_count[b * N_ + i], 1);
        if (pos < CAP)
            row_edges[(size_t)(b * N_ + i) * CAP + pos] =
                make_int2(e | (j << 16), __float_as_int(a));
    }
}

// ---------------------------------------------------------------------------
// row_fused: per-row scoring + sparse softmax + PV, bf16 QKV.
// grid = (N, B), block = 256.  O written bf16 pre-swizzled for out_mfma.
// ---------------------------------------------------------------------------
__global__ __launch_bounds__(256) void row_fused(
    const u16* __restrict__ QKV, const float* __restrict__ vsum,
    const int* __restrict__ row_count, const int2* __restrict__ row_edges,
    u16* __restrict__ Obf)
{
    const int row = blockIdx.x;
    const int b   = blockIdx.y;
    const int t = threadIdx.x;
    const int wave = t >> 6, lane = t & 63;
    int cnt = row_count[b * N_ + row];
    if (cnt > CAP) cnt = CAP;

    __shared__ int   le[CAP];
    __shared__ int   lj[CAP];
    __shared__ float lws[CAP];
    __shared__ float sexp[CAP * H_];
    __shared__ unsigned char lw[CAP];

    if (t < cnt) {
        int2 v = row_edges[(size_t)(b * N_ + row) * CAP + t];
        le[t] = v.x & 0xFFFF;
        lj[t] = v.x >> 16;
        lws[t] = __int_as_float(v.y);
    }
    __syncthreads();
    if (t < cnt) {                       // last-e-wins dedup
        const int j = lj[t], e = le[t];
        bool w = true;
        for (int q2 = 0; q2 < cnt; ++q2)
            if (lj[q2] == j && le[q2] > e) { w = false; break; }
        lw[t] = w ? 1 : 0;
    }
    __syncthreads();

    const char* base = (const char*)QKV;
    // q row: 1KB bf16; lane holds 8 elems; head = lane>>4
    const uint4 qv = *(const uint4*)(base + (size_t)(b * N_ + row) * 3072 + lane * 16);
    const float q0=blo(qv.x), q1=bhi(qv.x), q2=blo(qv.y), q3=bhi(qv.y);
    const float q4=blo(qv.z), q5=bhi(qv.z), q6=blo(qv.w), q7=bhi(qv.w);
    const float rs = 0.02209708691207961f;   // 1/sqrt(2048)

    for (int p = wave; p < cnt; p += 4) {
        if (!lw[p]) continue;
        const int j = lj[p];
        const uint4 kv = *(const uint4*)(base + (size_t)(b * N_ + j) * 3072 + 1024 + lane * 16);
        float s = q0*blo(kv.x) + q1*bhi(kv.x) + q2*blo(kv.y) + q3*bhi(kv.y)
                + q4*blo(kv.z) + q5*bhi(kv.z) + q6*blo(kv.w) + q7*bhi(kv.w);
        s += __shfl_xor(s, 1);
        s += __shfl_xor(s, 2);
        s += __shfl_xor(s, 4);
        s += __shfl_xor(s, 8);
        if ((lane & 15) == 0)
            sexp[p * H_ + (lane >> 4)] = expf(s * rs * lws[p]);
    }
    __syncthreads();

    const int h = wave;
    float2 acc = make_float2(0.f, 0.f);
    float dsum = 0.f;
    for (int p = 0; p < cnt; ++p) {
        if (!lw[p]) continue;
        const float x = sexp[p * H_ + h] - 1.f;
        dsum += x;
        const uint32 vv = *(const uint32*)(base + (size_t)(b * N_ + lj[p]) * 3072
                                           + 2048 + h * 256 + lane * 4);
        acc.x = fmaf(x, blo(vv), acc.x);
        acc.y = fmaf(x, bhi(vv), acc.y);
    }
    const float inv = 1.0f / ((float)N_ + dsum);
    const float2 vs = *(const float2*)(vsum + (b * H_ + h) * 128 + lane * 2);
    const size_t R = (size_t)b * N_ + row;
    const int off = h * 256 + ((lane * 4) ^ ((int)(R & 7) << 4));
    const u16 o0 = f2b((vs.x + acc.x) * inv);
    const u16 o1 = f2b((vs.y + acc.y) * inv);
    *(u16*)((char*)Obf + R * 1024 + off)     = o0;
    *(u16*)((char*)Obf + R * 1024 + off + 2) = o1;
}

// ---------------------------------------------------------------------------
// out_mfma: d_out[8192][128] f32 = Obf[8192][512] x OWbf[128][512]^T + out_b
// grid = 128 row-blocks (M-tile 64), 4 waves (2x2), wave tile 32x64.
// K-loop: 4 steps of BK=128.
// ---------------------------------------------------------------------------
__global__ __launch_bounds__(256) void out_mfma(
    const u16* __restrict__ Obf, const u16* __restrict__ OWbf,
    const float* __restrict__ bo, float* __restrict__ Out)
{
    __shared__ u16 As[64 * 128];    // 16KB
    __shared__ u16 Bs[128 * 128];   // 32KB
    const int rb = blockIdx.x;
    const int t = threadIdx.x;
    const int lane = t & 63, wave = t >> 6;
    const int wm = wave >> 1, wn = wave & 1;
    const int l15 = lane & 15, l4 = lane >> 4;

    f32x4 acc[2][4];
    #pragma unroll
    for (int i = 0; i < 2; ++i)
        #pragma unroll
        for (int j = 0; j < 4; ++j) acc[i][j] = (f32x4){0.f, 0.f, 0.f, 0.f};

    for (int kc = 0; kc < 4; ++kc) {
        #pragma unroll
        for (int q = 0; q < 4; ++q) {       // A: 16KB
            const int o = t * 16 + q * 4096;
            const int arow = o >> 8, ob = o & 255;
            g2l16((const char*)Obf + (size_t)(rb * 64 + arow) * 1024 + kc * 256 + ob,
                  (char*)As + o);
        }
        #pragma unroll
        for (int q = 0; q < 8; ++q) {       // B: 32KB
            const int o = t * 16 + q * 4096;
            const int c = o >> 8, ob = o & 255;
            g2l16((const char*)OWbf + (size_t)c * 1024 + kc * 256 + ob,
                  (char*)Bs + o);
        }
        __syncthreads();
        #pragma unroll
        for (int ks = 0; ks < 4; ++ks) {
            const int kb = ks * 64 + l4 * 16;
            bf16x8 a[2], bb[4];
            #pragma unroll
            for (int fm = 0; fm < 2; ++fm) {
                const int row = wm * 32 + fm * 16 + l15;
                a[fm] = *(const bf16x8*)((const char*)As + row * 256 + (kb ^ ((row & 7) << 4)));
            }
            #pragma unroll
            for (int fn = 0; fn < 4; ++fn) {
                const int col = wn * 64 + fn * 16 + l15;
                bb[fn] = *(const bf16x8*)((const char*)Bs + col * 256 + (kb ^ ((col & 7) << 4)));
            }
            #pragma unroll
            for (int fm = 0; fm < 2; ++fm)
                #pragma unroll
                for (int fn = 0; fn < 4; ++fn)
                    acc[fm][fn] = __builtin_amdgcn_mfma_f32_16x16x32_bf16(
                        a[fm], bb[fn], acc[fm][fn], 0, 0, 0);
        }
        __syncthreads();
    }

    #pragma unroll
    for (int fm = 0; fm < 2; ++fm)
        #pragma unroll
        for (int fn = 0; fn < 4; ++fn) {
            const int col = wn * 64 + fn * 16 + l15;
            const float bv = bo[col];
            #pragma unroll
            for (int r = 0; r < 4; ++r) {
                const int row = rb * 64 + wm * 32 + fm * 16 + l4 * 4 + r;
                Out[(size_t)row * OUT_ + col] = acc[fm][fn][r] + bv;
            }
        }
}

// ---------------------------------------------------------------------------
extern "C" void kernel_launch(void* const* d_in, const int* in_sizes, int n_in,
                              void* d_out, int out_size, void* d_ws, size_t ws_size,
                              hipStream_t stream)
{
    const float* x     = (const float*)d_in[0];
    const int*   nidx  = (const int*)  d_in[1];
    const float* attr  = (const float*)d_in[2];
    const float* wq_w  = (const float*)d_in[3];
    const float* wq_b  = (const float*)d_in[4];
    const float* wk_w  = (const float*)d_in[5];
    const float* wk_b  = (const float*)d_in[6];
    const float* wv_w  = (const float*)d_in[7];
    const float* wv_b  = (const float*)d_in[8];
    const float* out_w = (const float*)d_in[9];
    const float* out_b = (const float*)d_in[10];
    float* out = (float*)d_out;

    char* ws = (char*)d_ws;
    size_t off = 0;
    auto alloc = [&](size_t bytes) -> char* {
        char* p = ws + off;
        off += (bytes + 255) & ~(size_t)255;
        return p;
    };
    u16*  Xbf  = (u16*)alloc((size_t)M_ * D_ * 2);          // 2MB
    u16*  Wbf  = (u16*)alloc((size_t)12 * D_ * D_ * 2);     // 384KB
    float* biasf = (float*)alloc((size_t)12 * D_ * 4);      // 6KB
    u16*  QKV  = (u16*)alloc((size_t)M_ * C3_ * 2);         // 24MB
    u16*  OWbf = (u16*)alloc((size_t)OUT_ * HD_ * 2);       // 128KB
    u16*  Obf  = (u16*)alloc((size_t)M_ * HD_ * 2);         // 8MB
    float* vsum = (float*)alloc((size_t)B_ * H_ * D_ * 4);  // 8KB
    int*  row_count = (int*)alloc((size_t)B_ * N_ * 4);
    int2* row_edges = (int2*)alloc((size_t)B_ * N_ * CAP * 8);

    hipMemsetAsync(row_count, 0, (size_t)B_ * N_ * 4, stream);
    hipMemsetAsync(vsum, 0, (size_t)B_ * H_ * D_ * 4, stream);

    cast_x <<<M_ * D_ / 8 / 256, 256, 0, stream>>>(x, Xbf);
    cast_w <<<12, 256, 0, stream>>>(wq_w, wk_w, wv_w, wq_b, wk_b, wv_b, Wbf, biasf);
    cast_ow<<<OUT_ * HD_ / 8 / 256, 256, 0, stream>>>(out_w, OWbf);

    qkv_mfma<<<64 * 12, 256, 0, stream>>>(Xbf, Wbf, biasf, QKV);
    vsum_kernel<<<dim3(B_ * H_, 8), 128, 0, stream>>>(QKV, vsum);
    append_kernel<<<(B_ * E_) / 32, 256, 0, stream>>>(nidx, attr, row_count, row_edges);
    row_fused<<<dim3(N_, B_), 256, 0, stream>>>(QKV, vsum, row_count, row_edges, Obf);
    out_mfma<<<M_ / 64, 256, 0, stream>>>(Obf, OWbf, out_b, out);
}

// Round 4
// 87.793 us; speedup vs baseline: 2.9514x; 1.5136x over previous
//
#include <hip/hip_runtime.h>
#include <hip/hip_bf16.h>
#include <math.h>

// Problem constants
constexpr int B_ = 4;
constexpr int N_ = 2048;
constexpr int D_ = 128;
constexpr int H_ = 4;
constexpr int E_ = 32768;
constexpr int W_ = 8;
constexpr int OUT_ = 128;
constexpr int HD_ = H_ * D_;    // 512
constexpr int C3_ = 3 * HD_;    // 1536 combined QKV cols
constexpr int CAP = 64;         // max edges per row bucket (Poisson(16))
constexpr int M_ = B_ * N_;     // 8192 rows

typedef __attribute__((ext_vector_type(8))) __bf16 bf16x8;
typedef __attribute__((ext_vector_type(4))) float f32x4;
typedef unsigned int uint32;
typedef unsigned short u16;

__device__ __forceinline__ u16 f2b(float f) {
    __hip_bfloat16 h = __float2bfloat16(f);
    return *(u16*)&h;
}
__device__ __forceinline__ float blo(uint32 u) { return __uint_as_float(u << 16); }
__device__ __forceinline__ float bhi(uint32 u) { return __uint_as_float(u & 0xffff0000u); }

// async 16B global->LDS copy (dest = wave-uniform base + lane*16)
__device__ __forceinline__ void g2l16(const void* g, void* l) {
    __builtin_amdgcn_global_load_lds(
        (const __attribute__((address_space(1))) unsigned int*)(uintptr_t)g,
        (__attribute__((address_space(3))) unsigned int*)(uintptr_t)l,
        16, 0, 0);
}

// ---------------------------------------------------------------------------
// prep_kernel: fused cast_x + cast_w + cast_ow + edge append.
// blocks [0,512): cast x -> Xbf (swizzled)
// blocks [512,608): cast 12 weight mats -> Wbf (swizzled) + bias copy
// blocks [608,640): cast out_w -> OWbf (swizzled)
// blocks [640,4736): edge bucket append + wsum
// ---------------------------------------------------------------------------
__global__ __launch_bounds__(256) void prep_kernel(
    const float* __restrict__ X,
    const float* __restrict__ wq, const float* __restrict__ wk, const float* __restrict__ wv,
    const float* __restrict__ bq, const float* __restrict__ bk, const float* __restrict__ bv,
    const float* __restrict__ OW,
    const int* __restrict__ nidx, const float* __restrict__ attr,
    u16* __restrict__ Xbf, u16* __restrict__ Wbf, float* __restrict__ biasf,
    u16* __restrict__ OWbf,
    int* __restrict__ row_count, int2* __restrict__ row_edges)
{
    const int blk = blockIdx.x;
    if (blk < 512) {                       // ---- cast_x ----
        const int tid = blk * 256 + threadIdx.x;
        const int row = tid >> 4, sub = tid & 15;
        const float4 f0 = *(const float4*)(X + (size_t)row * 128 + sub * 8);
        const float4 f1 = *(const float4*)(X + (size_t)row * 128 + sub * 8 + 4);
        union { u16 u[8]; uint4 v; } pk;
        pk.u[0]=f2b(f0.x); pk.u[1]=f2b(f0.y); pk.u[2]=f2b(f0.z); pk.u[3]=f2b(f0.w);
        pk.u[4]=f2b(f1.x); pk.u[5]=f2b(f1.y); pk.u[6]=f2b(f1.z); pk.u[7]=f2b(f1.w);
        const int ob = row * 256 + ((sub * 16) ^ ((row & 7) << 4));
        *(uint4*)((char*)Xbf + ob) = pk.v;
    } else if (blk < 608) {                // ---- cast_w + bias ----
        const int c = (blk - 512) * 256 + threadIdx.x;   // 0..24575
        const int g = c >> 11, idx = c & 2047;
        const int t3 = g >> 2, h = g & 3;
        const float* Wsrc = (t3 == 0 ? wq : t3 == 1 ? wk : wv) + (size_t)h * 128 * 128;
        const int e = idx >> 4, sub = idx & 15;
        const float4 f0 = *(const float4*)(Wsrc + (size_t)e * 128 + sub * 8);
        const float4 f1 = *(const float4*)(Wsrc + (size_t)e * 128 + sub * 8 + 4);
        union { u16 u[8]; uint4 v; } pk;
        pk.u[0]=f2b(f0.x); pk.u[1]=f2b(f0.y); pk.u[2]=f2b(f0.z); pk.u[3]=f2b(f0.w);
        pk.u[4]=f2b(f1.x); pk.u[5]=f2b(f1.y); pk.u[6]=f2b(f1.z); pk.u[7]=f2b(f1.w);
        const int ob = g * 32768 + e * 256 + ((sub * 16) ^ ((e & 7) << 4));
        *(uint4*)((char*)Wbf + ob) = pk.v;
        if (idx < 128) {
            const float* Bsrc = (t3 == 0 ? bq : t3 == 1 ? bk : bv) + h * 128;
            biasf[g * 128 + idx] = Bsrc[idx];
        }
    } else if (blk < 640) {                // ---- cast_ow ----
        const int tid = (blk - 608) * 256 + threadIdx.x;  // 0..8191
        const int c = tid >> 6, sub = tid & 63;
        const float4 f0 = *(const float4*)(OW + (size_t)c * 512 + sub * 8);
        const float4 f1 = *(const float4*)(OW + (size_t)c * 512 + sub * 8 + 4);
        union { u16 u[8]; uint4 v; } pk;
        pk.u[0]=f2b(f0.x); pk.u[1]=f2b(f0.y); pk.u[2]=f2b(f0.z); pk.u[3]=f2b(f0.w);
        pk.u[4]=f2b(f1.x); pk.u[5]=f2b(f1.y); pk.u[6]=f2b(f1.z); pk.u[7]=f2b(f1.w);
        const int ob = c * 1024 + ((sub * 16) ^ ((c & 7) << 4));
        *(uint4*)((char*)OWbf + ob) = pk.v;
    } else {                               // ---- edge append ----
        const int wave = threadIdx.x >> 6;
        const int lane = threadIdx.x & 63;
        const int gw = (blk - 640) * 4 + wave;
        const int e0g = gw * 8;
        const int b = e0g / E_;
        const int e0 = e0g % E_;

        float a = attr[((size_t)b * E_ + e0) * W_ + lane];
        a += __shfl_xor(a, 1);
        a += __shfl_xor(a, 2);
        a += __shfl_xor(a, 4);

        if ((lane & 7) == 0) {
            const int sub = lane >> 3;
            const int e = e0 + sub;
            const int i = nidx[b * 2 * E_ + e];
            const int j = nidx[b * 2 * E_ + E_ + e];
            const int pos = atomicAdd(&row_count[b * N_ + i], 1);
            if (pos < CAP)
                row_edges[(size_t)(b * N_ + i) * CAP + pos] =
                    make_int2(e | (j << 16), __float_as_int(a));
        }
    }
}

// ---------------------------------------------------------------------------
// qkv_mfma: QKV[8192][1536] bf16 = Xbf[8192][128] x Wbf[12 x 128][128]^T + bias
// grid = 768 = 64 row-blocks x 12 col-blocks.  Tile 128x128, K=128 (no K loop).
// V col-blocks (g>=8) also column-reduce f32 accs into vsum via atomics.
// ---------------------------------------------------------------------------
__global__ __launch_bounds__(256) void qkv_mfma(
    const u16* __restrict__ Xbf, const u16* __restrict__ Wbf,
    const float* __restrict__ biasf, u16* __restrict__ QKV,
    float* __restrict__ vsum)
{
    __shared__ u16 As[128 * 128];
    __shared__ u16 Bs[128 * 128];
    const int rb = blockIdx.x & 63;
    const int g  = blockIdx.x >> 6;
    const int t = threadIdx.x;
    const int lane = t & 63, wave = t >> 6;
    const int wm = wave >> 1, wn = wave & 1;
    const int l15 = lane & 15, l4 = lane >> 4;

    const char* Asrc = (const char*)(Xbf + (size_t)rb * 128 * 128);
    const char* Bsrc = (const char*)(Wbf + (size_t)g  * 128 * 128);
    #pragma unroll
    for (int q = 0; q < 8; ++q) {
        const int o = t * 16 + q * 4096;
        g2l16(Asrc + o, (char*)As + o);
        g2l16(Bsrc + o, (char*)Bs + o);
    }
    __syncthreads();

    f32x4 acc[4][4];
    #pragma unroll
    for (int i = 0; i < 4; ++i)
        #pragma unroll
        for (int j = 0; j < 4; ++j) acc[i][j] = (f32x4){0.f, 0.f, 0.f, 0.f};

    #pragma unroll
    for (int ks = 0; ks < 4; ++ks) {
        const int kb = ks * 64 + l4 * 16;
        bf16x8 a[4], bb[4];
        #pragma unroll
        for (int fm = 0; fm < 4; ++fm) {
            const int row = wm * 64 + fm * 16 + l15;
            a[fm] = *(const bf16x8*)((const char*)As + row * 256 + (kb ^ ((row & 7) << 4)));
        }
        #pragma unroll
        for (int fn = 0; fn < 4; ++fn) {
            const int col = wn * 64 + fn * 16 + l15;
            bb[fn] = *(const bf16x8*)((const char*)Bs + col * 256 + (kb ^ ((col & 7) << 4)));
        }
        #pragma unroll
        for (int fm = 0; fm < 4; ++fm)
            #pragma unroll
            for (int fn = 0; fn < 4; ++fn)
                acc[fm][fn] = __builtin_amdgcn_mfma_f32_16x16x32_bf16(
                    a[fm], bb[fn], acc[fm][fn], 0, 0, 0);
    }

    #pragma unroll
    for (int fm = 0; fm < 4; ++fm)
        #pragma unroll
        for (int fn = 0; fn < 4; ++fn) {
            const int col = wn * 64 + fn * 16 + l15;
            const float bv = biasf[g * 128 + col];
            const int gcol = g * 128 + col;
            #pragma unroll
            for (int r = 0; r < 4; ++r) {
                const int row = rb * 128 + wm * 64 + fm * 16 + l4 * 4 + r;
                QKV[(size_t)row * C3_ + gcol] = f2b(acc[fm][fn][r] + bv);
            }
        }

    if (g >= 8) {   // fused V column-sum (includes bias via +64*bv per wave)
        const int h = g - 8;
        const int b = rb >> 4;      // 16 row-blocks per batch
        #pragma unroll
        for (int fn = 0; fn < 4; ++fn) {
            float s = 0.f;
            #pragma unroll
            for (int fm = 0; fm < 4; ++fm)
                #pragma unroll
                for (int r = 0; r < 4; ++r) s += acc[fm][fn][r];
            s += __shfl_xor(s, 16);
            s += __shfl_xor(s, 32);
            if (l4 == 0) {
                const int col = wn * 64 + fn * 16 + l15;
                const float bv = biasf[g * 128 + col];
                atomicAdd(&vsum[(b * H_ + h) * 128 + col], s + 64.f * bv);
            }
        }
    }
}

// ---------------------------------------------------------------------------
// row_fused: wave-per-row scoring + sparse softmax + PV, no __syncthreads.
// grid = (N/4, B), block = 256 (4 independent waves, wave = row).
// Lane owns 8 contiguous elems (head = lane>>4); K/V rows load as 1 dwordx4.
// ---------------------------------------------------------------------------
__global__ __launch_bounds__(256) void row_fused(
    const u16* __restrict__ QKV, const float* __restrict__ vsum,
    const int* __restrict__ row_count, const int2* __restrict__ row_edges,
    u16* __restrict__ Obf)
{
    const int t = threadIdx.x;
    const int wave = t >> 6, lane = t & 63;
    const int row = blockIdx.x * 4 + wave;
    const int b = blockIdx.y;
    const int R = b * N_ + row;
    int cnt = row_count[R];
    if (cnt > CAP) cnt = CAP;

    // edge entries register-resident: lane p < cnt holds entry p
    int ej = 0; float ws = 0.f;
    if (lane < cnt) {
        const int2 v = row_edges[(size_t)R * CAP + lane];
        ej = v.x; ws = __int_as_float(v.y);
    }
    // last-e-wins dedup via shfl broadcast (winner = max e per j)
    const int myj = ej >> 16, mye = ej & 0xFFFF;
    bool win = (lane < cnt);
    for (int p = 0; p < cnt; ++p) {
        const int oj = __shfl(ej, p);
        if (win && (oj >> 16) == myj && (oj & 0xFFFF) > mye) win = false;
    }
    unsigned long long mask = __ballot(win);

    const char* base = (const char*)QKV;
    const uint4 qv = *(const uint4*)(base + (size_t)R * 3072 + lane * 16);
    const float q0=blo(qv.x), q1=bhi(qv.x), q2=blo(qv.y), q3=bhi(qv.y),
                q4=blo(qv.z), q5=bhi(qv.z), q6=blo(qv.w), q7=bhi(qv.w);
    const float rs = 0.02209708691207961f;   // 1/sqrt(2048)

    float a0=0.f,a1=0.f,a2=0.f,a3=0.f,a4=0.f,a5=0.f,a6=0.f,a7=0.f;
    float dsum = 0.f;

    while (mask) {
        const int p = (int)__ffsll((long long)mask) - 1;
        mask &= mask - 1;
        const int j = __shfl(ej, p) >> 16;
        const float wsp = __shfl(ws, p);
        const char* nb = base + (size_t)(b * N_ + j) * 3072;
        const uint4 kv = *(const uint4*)(nb + 1024 + lane * 16);
        const uint4 vv = *(const uint4*)(nb + 2048 + lane * 16);
        float s = q0*blo(kv.x) + q1*bhi(kv.x) + q2*blo(kv.y) + q3*bhi(kv.y)
                + q4*blo(kv.z) + q5*bhi(kv.z) + q6*blo(kv.w) + q7*bhi(kv.w);
        s += __shfl_xor(s, 1);
        s += __shfl_xor(s, 2);
        s += __shfl_xor(s, 4);
        s += __shfl_xor(s, 8);       // 16-lane group = one head
        const float x = expf(s * rs * wsp) - 1.f;
        dsum += x;
        a0 = fmaf(x, blo(vv.x), a0); a1 = fmaf(x, bhi(vv.x), a1);
        a2 = fmaf(x, blo(vv.y), a2); a3 = fmaf(x, bhi(vv.y), a3);
        a4 = fmaf(x, blo(vv.z), a4); a5 = fmaf(x, bhi(vv.z), a5);
        a6 = fmaf(x, blo(vv.w), a6); a7 = fmaf(x, bhi(vv.w), a7);
    }

    const float inv = 1.0f / (2048.0f + dsum);
    const float* vsp = vsum + (b * H_ + (lane >> 4)) * 128 + (lane & 15) * 8;
    const float4 vs0 = *(const float4*)vsp;
    const float4 vs1 = *(const float4*)(vsp + 4);
    union { u16 u[8]; uint4 v; } o;
    o.u[0]=f2b((vs0.x+a0)*inv); o.u[1]=f2b((vs0.y+a1)*inv);
    o.u[2]=f2b((vs0.z+a2)*inv); o.u[3]=f2b((vs0.w+a3)*inv);
    o.u[4]=f2b((vs1.x+a4)*inv); o.u[5]=f2b((vs1.y+a5)*inv);
    o.u[6]=f2b((vs1.z+a6)*inv); o.u[7]=f2b((vs1.w+a7)*inv);
    const int ob = ((lane >> 4) << 8) + (((lane & 15) * 16) ^ ((R & 7) << 4));
    *(uint4*)((char*)Obf + (size_t)R * 1024 + ob) = o.v;
}

// ---------------------------------------------------------------------------
// out_mfma: d_out[8192][128] f32 = Obf[8192][512] x OWbf[128][512]^T + out_b
// grid = 128 row-blocks (M-tile 64), 4 waves (2x2), wave tile 32x64.
// ---------------------------------------------------------------------------
__global__ __launch_bounds__(256) void out_mfma(
    const u16* __restrict__ Obf, const u16* __restrict__ OWbf,
    const float* __restrict__ bo, float* __restrict__ Out)
{
    __shared__ u16 As[64 * 128];    // 16KB
    __shared__ u16 Bs[128 * 128];   // 32KB
    const int rb = blockIdx.x;
    const int t = threadIdx.x;
    const int lane = t & 63, wave = t >> 6;
    const int wm = wave >> 1, wn = wave & 1;
    const int l15 = lane & 15, l4 = lane >> 4;

    f32x4 acc[2][4];
    #pragma unroll
    for (int i = 0; i < 2; ++i)
        #pragma unroll
        for (int j = 0; j < 4; ++j) acc[i][j] = (f32x4){0.f, 0.f, 0.f, 0.f};

    for (int kc = 0; kc < 4; ++kc) {
        #pragma unroll
        for (int q = 0; q < 4; ++q) {       // A: 16KB
            const int o = t * 16 + q * 4096;
            const int arow = o >> 8, ob = o & 255;
            g2l16((const char*)Obf + (size_t)(rb * 64 + arow) * 1024 + kc * 256 + ob,
                  (char*)As + o);
        }
        #pragma unroll
        for (int q = 0; q < 8; ++q) {       // B: 32KB
            const int o = t * 16 + q * 4096;
            const int c = o >> 8, ob = o & 255;
            g2l16((const char*)OWbf + (size_t)c * 1024 + kc * 256 + ob,
                  (char*)Bs + o);
        }
        __syncthreads();
        #pragma unroll
        for (int ks = 0; ks < 4; ++ks) {
            const int kb = ks * 64 + l4 * 16;
            bf16x8 a[2], bb[4];
            #pragma unroll
            for (int fm = 0; fm < 2; ++fm) {
                const int row = wm * 32 + fm * 16 + l15;
                a[fm] = *(const bf16x8*)((const char*)As + row * 256 + (kb ^ ((row & 7) << 4)));
            }
            #pragma unroll
            for (int fn = 0; fn < 4; ++fn) {
                const int col = wn * 64 + fn * 16 + l15;
                bb[fn] = *(const bf16x8*)((const char*)Bs + col * 256 + (kb ^ ((col & 7) << 4)));
            }
            #pragma unroll
            for (int fm = 0; fm < 2; ++fm)
                #pragma unroll
                for (int fn = 0; fn < 4; ++fn)
                    acc[fm][fn] = __builtin_amdgcn_mfma_f32_16x16x32_bf16(
                        a[fm], bb[fn], acc[fm][fn], 0, 0, 0);
        }
        __syncthreads();
    }

    #pragma unroll
    for (int fm = 0; fm < 2; ++fm)
        #pragma unroll
        for (int fn = 0; fn < 4; ++fn) {
            const int col = wn * 64 + fn * 16 + l15;
            const float bv = bo[col];
            #pragma unroll
            for (int r = 0; r < 4; ++r) {
                const int row = rb * 64 + wm * 32 + fm * 16 + l4 * 4 + r;
                Out[(size_t)row * OUT_ + col] = acc[fm][fn][r] + bv;
            }
        }
}

// ---------------------------------------------------------------------------
extern "C" void kernel_launch(void* const* d_in, const int* in_sizes, int n_in,
                              void* d_out, int out_size, void* d_ws, size_t ws_size,
                              hipStream_t stream)
{
    const float* x     = (const float*)d_in[0];
    const int*   nidx  = (const int*)  d_in[1];
    const float* attr  = (const float*)d_in[2];
    const float* wq_w  = (const float*)d_in[3];
    const float* wq_b  = (const float*)d_in[4];
    const float* wk_w  = (const float*)d_in[5];
    const float* wk_b  = (const float*)d_in[6];
    const float* wv_w  = (const float*)d_in[7];
    const float* wv_b  = (const float*)d_in[8];
    const float* out_w = (const float*)d_in[9];
    const float* out_b = (const float*)d_in[10];
    float* out = (float*)d_out;

    char* ws = (char*)d_ws;
    size_t off = 0;
    auto alloc = [&](size_t bytes) -> char* {
        char* p = ws + off;
        off += (bytes + 255) & ~(size_t)255;
        return p;
    };
    u16*  Xbf  = (u16*)alloc((size_t)M_ * D_ * 2);          // 2MB
    u16*  Wbf  = (u16*)alloc((size_t)12 * D_ * D_ * 2);     // 384KB
    float* biasf = (float*)alloc((size_t)12 * D_ * 4);      // 6KB
    u16*  QKV  = (u16*)alloc((size_t)M_ * C3_ * 2);         // 24MB
    u16*  OWbf = (u16*)alloc((size_t)OUT_ * HD_ * 2);       // 128KB
    u16*  Obf  = (u16*)alloc((size_t)M_ * HD_ * 2);         // 8MB
    float* vsum = (float*)alloc((size_t)B_ * H_ * D_ * 4);  // 8KB
    int*  row_count = (int*)alloc((size_t)B_ * N_ * 4);
    int2* row_edges = (int2*)alloc((size_t)B_ * N_ * CAP * 8);

    hipMemsetAsync(row_count, 0, (size_t)B_ * N_ * 4, stream);
    hipMemsetAsync(vsum, 0, (size_t)B_ * H_ * D_ * 4, stream);

    prep_kernel<<<640 + (B_ * E_) / 32, 256, 0, stream>>>(
        x, wq_w, wk_w, wv_w, wq_b, wk_b, wv_b, out_w, nidx, attr,
        Xbf, Wbf, biasf, OWbf, row_count, row_edges);
    qkv_mfma<<<64 * 12, 256, 0, stream>>>(Xbf, Wbf, biasf, QKV, vsum);
    row_fused<<<dim3(N_ / 4, B_), 256, 0, stream>>>(
        QKV, vsum, row_count, row_edges, Obf);
    out_mfma<<<M_ / 64, 256, 0, stream>>>(Obf, OWbf, out_b, out);
}

// Round 5
// 84.240 us; speedup vs baseline: 3.0759x; 1.0422x over previous
//
#include <hip/hip_runtime.h>
#include <hip/hip_bf16.h>
#include <math.h>

// Problem constants
constexpr int B_ = 4;
constexpr int N_ = 2048;
constexpr int D_ = 128;
constexpr int H_ = 4;
constexpr int E_ = 32768;
constexpr int W_ = 8;
constexpr int OUT_ = 128;
constexpr int HD_ = H_ * D_;    // 512
constexpr int C3_ = 3 * HD_;    // 1536 combined QKV cols
constexpr int CAP = 64;         // max edges per row bucket (Poisson(16))
constexpr int M_ = B_ * N_;     // 8192 rows

typedef __attribute__((ext_vector_type(8))) __bf16 bf16x8;
typedef __attribute__((ext_vector_type(4))) float f32x4;
typedef unsigned int uint32;
typedef unsigned short u16;

__device__ __forceinline__ u16 f2b(float f) {
    __hip_bfloat16 h = __float2bfloat16(f);
    return *(u16*)&h;
}
__device__ __forceinline__ float blo(uint32 u) { return __uint_as_float(u << 16); }
__device__ __forceinline__ float bhi(uint32 u) { return __uint_as_float(u & 0xffff0000u); }

// async 16B global->LDS copy (dest = wave-uniform base + lane*16)
__device__ __forceinline__ void g2l16(const void* g, void* l) {
    __builtin_amdgcn_global_load_lds(
        (const __attribute__((address_space(1))) unsigned int*)(uintptr_t)g,
        (__attribute__((address_space(3))) unsigned int*)(uintptr_t)l,
        16, 0, 0);
}

// ---------------------------------------------------------------------------
// prep_kernel: fused casts + zero(row_count, vsum).
// blocks [0,512): cast x -> Xbf (swizzled)
// blocks [512,608): cast 12 weight mats -> Wbf (swizzled) + bias copy
// blocks [608,640): cast out_w -> OWbf (swizzled)
// block 640: zero row_count (32KB) + vsum (8KB)
// ---------------------------------------------------------------------------
__global__ __launch_bounds__(256) void prep_kernel(
    const float* __restrict__ X,
    const float* __restrict__ wq, const float* __restrict__ wk, const float* __restrict__ wv,
    const float* __restrict__ bq, const float* __restrict__ bk, const float* __restrict__ bv,
    const float* __restrict__ OW,
    u16* __restrict__ Xbf, u16* __restrict__ Wbf, float* __restrict__ biasf,
    u16* __restrict__ OWbf,
    int* __restrict__ row_count, float* __restrict__ vsum)
{
    const int blk = blockIdx.x;
    if (blk < 512) {                       // ---- cast_x ----
        const int tid = blk * 256 + threadIdx.x;
        const int row = tid >> 4, sub = tid & 15;
        const float4 f0 = *(const float4*)(X + (size_t)row * 128 + sub * 8);
        const float4 f1 = *(const float4*)(X + (size_t)row * 128 + sub * 8 + 4);
        union { u16 u[8]; uint4 v; } pk;
        pk.u[0]=f2b(f0.x); pk.u[1]=f2b(f0.y); pk.u[2]=f2b(f0.z); pk.u[3]=f2b(f0.w);
        pk.u[4]=f2b(f1.x); pk.u[5]=f2b(f1.y); pk.u[6]=f2b(f1.z); pk.u[7]=f2b(f1.w);
        const int ob = row * 256 + ((sub * 16) ^ ((row & 7) << 4));
        *(uint4*)((char*)Xbf + ob) = pk.v;
    } else if (blk < 608) {                // ---- cast_w + bias ----
        const int c = (blk - 512) * 256 + threadIdx.x;   // 0..24575
        const int g = c >> 11, idx = c & 2047;
        const int t3 = g >> 2, h = g & 3;
        const float* Wsrc = (t3 == 0 ? wq : t3 == 1 ? wk : wv) + (size_t)h * 128 * 128;
        const int e = idx >> 4, sub = idx & 15;
        const float4 f0 = *(const float4*)(Wsrc + (size_t)e * 128 + sub * 8);
        const float4 f1 = *(const float4*)(Wsrc + (size_t)e * 128 + sub * 8 + 4);
        union { u16 u[8]; uint4 v; } pk;
        pk.u[0]=f2b(f0.x); pk.u[1]=f2b(f0.y); pk.u[2]=f2b(f0.z); pk.u[3]=f2b(f0.w);
        pk.u[4]=f2b(f1.x); pk.u[5]=f2b(f1.y); pk.u[6]=f2b(f1.z); pk.u[7]=f2b(f1.w);
        const int ob = g * 32768 + e * 256 + ((sub * 16) ^ ((e & 7) << 4));
        *(uint4*)((char*)Wbf + ob) = pk.v;
        if (idx < 128) {
            const float* Bsrc = (t3 == 0 ? bq : t3 == 1 ? bk : bv) + h * 128;
            biasf[g * 128 + idx] = Bsrc[idx];
        }
    } else if (blk < 640) {                // ---- cast_ow ----
        const int tid = (blk - 608) * 256 + threadIdx.x;  // 0..8191
        const int c = tid >> 6, sub = tid & 63;
        const float4 f0 = *(const float4*)(OW + (size_t)c * 512 + sub * 8);
        const float4 f1 = *(const float4*)(OW + (size_t)c * 512 + sub * 8 + 4);
        union { u16 u[8]; uint4 v; } pk;
        pk.u[0]=f2b(f0.x); pk.u[1]=f2b(f0.y); pk.u[2]=f2b(f0.z); pk.u[3]=f2b(f0.w);
        pk.u[4]=f2b(f1.x); pk.u[5]=f2b(f1.y); pk.u[6]=f2b(f1.z); pk.u[7]=f2b(f1.w);
        const int ob = c * 1024 + ((sub * 16) ^ ((c & 7) << 4));
        *(uint4*)((char*)OWbf + ob) = pk.v;
    } else {                               // ---- zero row_count + vsum ----
        const uint4 z = make_uint4(0, 0, 0, 0);
        uint4* rc = (uint4*)row_count;     // 2048 uint4 = 32KB
        #pragma unroll
        for (int q = 0; q < 8; ++q) rc[threadIdx.x + q * 256] = z;
        uint4* vs = (uint4*)vsum;          // 512 uint4 = 8KB
        #pragma unroll
        for (int q = 0; q < 2; ++q) vs[threadIdx.x + q * 256] = z;
    }
}

// ---------------------------------------------------------------------------
// append_kernel: edges -> per-row buckets + wsum.  8 edges/wave.
// Must run AFTER prep (zeroed row_count).
// ---------------------------------------------------------------------------
__global__ __launch_bounds__(256) void append_kernel(
    const int* __restrict__ nidx, const float* __restrict__ attr,
    int* __restrict__ row_count, int2* __restrict__ row_edges)
{
    const int wave = threadIdx.x >> 6;
    const int lane = threadIdx.x & 63;
    const int gw = blockIdx.x * 4 + wave;
    const int e0g = gw * 8;
    const int b = e0g / E_;
    const int e0 = e0g % E_;

    float a = attr[((size_t)b * E_ + e0) * W_ + lane];
    a += __shfl_xor(a, 1);
    a += __shfl_xor(a, 2);
    a += __shfl_xor(a, 4);

    if ((lane & 7) == 0) {
        const int sub = lane >> 3;
        const int e = e0 + sub;
        const int i = nidx[b * 2 * E_ + e];
        const int j = nidx[b * 2 * E_ + E_ + e];
        const int pos = atomicAdd(&row_count[b * N_ + i], 1);
        if (pos < CAP)
            row_edges[(size_t)(b * N_ + i) * CAP + pos] =
                make_int2(e | (j << 16), __float_as_int(a));
    }
}

// ---------------------------------------------------------------------------
// qkv_mfma: QKV[8192][1536] bf16 = Xbf[8192][128] x Wbf[12 x 128][128]^T + bias
// grid = 768 = 64 row-blocks x 12 col-blocks.  Tile 128x128, K=128 (no K loop).
// V col-blocks (g>=8) column-reduce into vsum via atomics.
// Epilogue repacks C through LDS for coalesced uint4 stores.
// ---------------------------------------------------------------------------
__global__ __launch_bounds__(256) void qkv_mfma(
    const u16* __restrict__ Xbf, const u16* __restrict__ Wbf,
    const float* __restrict__ biasf, u16* __restrict__ QKV,
    float* __restrict__ vsum)
{
    __shared__ u16 As[128 * 128];
    __shared__ u16 Bs[128 * 128];
    const int rb = blockIdx.x & 63;
    const int g  = blockIdx.x >> 6;
    const int t = threadIdx.x;
    const int lane = t & 63, wave = t >> 6;
    const int wm = wave >> 1, wn = wave & 1;
    const int l15 = lane & 15, l4 = lane >> 4;

    const char* Asrc = (const char*)(Xbf + (size_t)rb * 128 * 128);
    const char* Bsrc = (const char*)(Wbf + (size_t)g  * 128 * 128);
    #pragma unroll
    for (int q = 0; q < 8; ++q) {
        const int o = t * 16 + q * 4096;
        g2l16(Asrc + o, (char*)As + o);
        g2l16(Bsrc + o, (char*)Bs + o);
    }
    __syncthreads();

    f32x4 acc[4][4];
    #pragma unroll
    for (int i = 0; i < 4; ++i)
        #pragma unroll
        for (int j = 0; j < 4; ++j) acc[i][j] = (f32x4){0.f, 0.f, 0.f, 0.f};

    #pragma unroll
    for (int ks = 0; ks < 4; ++ks) {
        const int kb = ks * 64 + l4 * 16;
        bf16x8 a[4], bb[4];
        #pragma unroll
        for (int fm = 0; fm < 4; ++fm) {
            const int row = wm * 64 + fm * 16 + l15;
            a[fm] = *(const bf16x8*)((const char*)As + row * 256 + (kb ^ ((row & 7) << 4)));
        }
        #pragma unroll
        for (int fn = 0; fn < 4; ++fn) {
            const int col = wn * 64 + fn * 16 + l15;
            bb[fn] = *(const bf16x8*)((const char*)Bs + col * 256 + (kb ^ ((col & 7) << 4)));
        }
        #pragma unroll
        for (int fm = 0; fm < 4; ++fm)
            #pragma unroll
            for (int fn = 0; fn < 4; ++fn)
                acc[fm][fn] = __builtin_amdgcn_mfma_f32_16x16x32_bf16(
                    a[fm], bb[fn], acc[fm][fn], 0, 0, 0);
    }

    __syncthreads();   // all reads of As done; reuse As for C repack

    // write acc (+bias) into As as swizzled bf16 [row][256B]
    #pragma unroll
    for (int fm = 0; fm < 4; ++fm)
        #pragma unroll
        for (int fn = 0; fn < 4; ++fn) {
            const int col = wn * 64 + fn * 16 + l15;
            const float bv = biasf[g * 128 + col];
            #pragma unroll
            for (int r = 0; r < 4; ++r) {
                const int row = wm * 64 + fm * 16 + l4 * 4 + r;
                *(u16*)((char*)As + row * 256 + ((col * 2) ^ ((row & 7) << 4))) =
                    f2b(acc[fm][fn][r] + bv);
            }
        }

    if (g >= 8) {   // fused V column-sum (includes bias via +64*bv per wave)
        const int h = g - 8;
        const int b = rb >> 4;      // 16 row-blocks per batch
        #pragma unroll
        for (int fn = 0; fn < 4; ++fn) {
            float s = 0.f;
            #pragma unroll
            for (int fm = 0; fm < 4; ++fm)
                #pragma unroll
                for (int r = 0; r < 4; ++r) s += acc[fm][fn][r];
            s += __shfl_xor(s, 16);
            s += __shfl_xor(s, 32);
            if (l4 == 0) {
                const int col = wn * 64 + fn * 16 + l15;
                const float bv = biasf[g * 128 + col];
                atomicAdd(&vsum[(b * H_ + h) * 128 + col], s + 64.f * bv);
            }
        }
    }
    __syncthreads();

    // coalesced store: 8 x uint4 per thread
    #pragma unroll
    for (int q = 0; q < 8; ++q) {
        const int idx = t + q * 256;          // chunk 0..2047
        const int row = idx >> 4, c = idx & 15;
        const uint4 v = *(const uint4*)((char*)As + row * 256 + ((c * 16) ^ ((row & 7) << 4)));
        *(uint4*)(QKV + (size_t)(rb * 128 + row) * C3_ + g * 128 + c * 8) = v;
    }
}

// ---------------------------------------------------------------------------
// row_fused: wave-per-row scoring + sparse softmax + PV, 1-ahead prefetch.
// grid = (N/4, B), block = 256 (4 independent waves, wave = row).
// ---------------------------------------------------------------------------
__global__ __launch_bounds__(256) void row_fused(
    const u16* __restrict__ QKV, const float* __restrict__ vsum,
    const int* __restrict__ row_count, const int2* __restrict__ row_edges,
    u16* __restrict__ Obf)
{
    const int t = threadIdx.x;
    const int wave = t >> 6, lane = t & 63;
    const int row = blockIdx.x * 4 + wave;
    const int b = blockIdx.y;
    const int R = b * N_ + row;
    int cnt = row_count[R];
    if (cnt > CAP) cnt = CAP;

    // edge entries register-resident: lane p < cnt holds entry p
    int ej = 0; float ws = 0.f;
    if (lane < cnt) {
        const int2 v = row_edges[(size_t)R * CAP + lane];
        ej = v.x; ws = __int_as_float(v.y);
    }
    // last-e-wins dedup via shfl broadcast (winner = max e per j)
    const int myj = ej >> 16, mye = ej & 0xFFFF;
    bool win = (lane < cnt);
    for (int p = 0; p < cnt; ++p) {
        const int oj = __shfl(ej, p);
        if (win && (oj >> 16) == myj && (oj & 0xFFFF) > mye) win = false;
    }
    unsigned long long m = __ballot(win);

    const char* base = (const char*)QKV;
    const uint4 qv = *(const uint4*)(base + (size_t)R * 3072 + lane * 16);
    const float q0=blo(qv.x), q1=bhi(qv.x), q2=blo(qv.y), q3=bhi(qv.y),
                q4=blo(qv.z), q5=bhi(qv.z), q6=blo(qv.w), q7=bhi(qv.w);
    const float rs = 0.02209708691207961f;   // 1/sqrt(2048)

    float a0=0.f,a1=0.f,a2=0.f,a3=0.f,a4=0.f,a5=0.f,a6=0.f,a7=0.f;
    float dsum = 0.f;

#define PROCESS(kv, vv, wsp)                                                  \
    {                                                                         \
        float s = q0*blo(kv.x) + q1*bhi(kv.x) + q2*blo(kv.y) + q3*bhi(kv.y)   \
                + q4*blo(kv.z) + q5*bhi(kv.z) + q6*blo(kv.w) + q7*bhi(kv.w);  \
        s += __shfl_xor(s, 1);                                                \
        s += __shfl_xor(s, 2);                                                \
        s += __shfl_xor(s, 4);                                                \
        s += __shfl_xor(s, 8);                                                \
        const float x = expf(s * rs * (wsp)) - 1.f;                           \
        dsum += x;                                                            \
        a0 = fmaf(x, blo(vv.x), a0); a1 = fmaf(x, bhi(vv.x), a1);             \
        a2 = fmaf(x, blo(vv.y), a2); a3 = fmaf(x, bhi(vv.y), a3);             \
        a4 = fmaf(x, blo(vv.z), a4); a5 = fmaf(x, bhi(vv.z), a5);             \
        a6 = fmaf(x, blo(vv.w), a6); a7 = fmaf(x, bhi(vv.w), a7);             \
    }

    if (m) {
        int p = (int)__ffsll(m) - 1; m &= m - 1;
        int jc = __shfl(ej, p) >> 16;
        float wc = __shfl(ws, p);
        const char* nb = base + (size_t)(b * N_ + jc) * 3072;
        uint4 kv = *(const uint4*)(nb + 1024 + lane * 16);
        uint4 vv = *(const uint4*)(nb + 2048 + lane * 16);
        while (m) {
            const int p2 = (int)__ffsll(m) - 1; m &= m - 1;
            const int j2 = __shfl(ej, p2) >> 16;
            const float w2 = __shfl(ws, p2);
            const char* nb2 = base + (size_t)(b * N_ + j2) * 3072;
            const uint4 kv2 = *(const uint4*)(nb2 + 1024 + lane * 16);   // prefetch
            const uint4 vv2 = *(const uint4*)(nb2 + 2048 + lane * 16);
            PROCESS(kv, vv, wc);
            kv = kv2; vv = vv2; wc = w2;
        }
        PROCESS(kv, vv, wc);
    }
#undef PROCESS

    const float inv = 1.0f / (2048.0f + dsum);
    const float* vsp = vsum + (b * H_ + (lane >> 4)) * 128 + (lane & 15) * 8;
    const float4 vs0 = *(const float4*)vsp;
    const float4 vs1 = *(const float4*)(vsp + 4);
    union { u16 u[8]; uint4 v; } o;
    o.u[0]=f2b((vs0.x+a0)*inv); o.u[1]=f2b((vs0.y+a1)*inv);
    o.u[2]=f2b((vs0.z+a2)*inv); o.u[3]=f2b((vs0.w+a3)*inv);
    o.u[4]=f2b((vs1.x+a4)*inv); o.u[5]=f2b((vs1.y+a5)*inv);
    o.u[6]=f2b((vs1.z+a6)*inv); o.u[7]=f2b((vs1.w+a7)*inv);
    const int ob = ((lane >> 4) << 8) + (((lane & 15) * 16) ^ ((R & 7) << 4));
    *(uint4*)((char*)Obf + (size_t)R * 1024 + ob) = o.v;
}

// ---------------------------------------------------------------------------
// out_mfma: d_out[8192][128] f32 = Obf[8192][512] x OWbf[128][512]^T + out_b
// grid = 128 row-blocks (M-tile 64), 4 waves (2x2), wave tile 32x64.
// ---------------------------------------------------------------------------
__global__ __launch_bounds__(256) void out_mfma(
    const u16* __restrict__ Obf, const u16* __restrict__ OWbf,
    const float* __restrict__ bo, float* __restrict__ Out)
{
    __shared__ u16 As[64 * 128];    // 16KB
    __shared__ u16 Bs[128 * 128];   // 32KB
    const int rb = blockIdx.x;
    const int t = threadIdx.x;
    const int lane = t & 63, wave = t >> 6;
    const int wm = wave >> 1, wn = wave & 1;
    const int l15 = lane & 15, l4 = lane >> 4;

    f32x4 acc[2][4];
    #pragma unroll
    for (int i = 0; i < 2; ++i)
        #pragma unroll
        for (int j = 0; j < 4; ++j) acc[i][j] = (f32x4){0.f, 0.f, 0.f, 0.f};

    for (int kc = 0; kc < 4; ++kc) {
        #pragma unroll
        for (int q = 0; q < 4; ++q) {       // A: 16KB
            const int o = t * 16 + q * 4096;
            const int arow = o >> 8, ob = o & 255;
            g2l16((const char*)Obf + (size_t)(rb * 64 + arow) * 1024 + kc * 256 + ob,
                  (char*)As + o);
        }
        #pragma unroll
        for (int q = 0; q < 8; ++q) {       // B: 32KB
            const int o = t * 16 + q * 4096;
            const int c = o >> 8, ob = o & 255;
            g2l16((const char*)OWbf + (size_t)c * 1024 + kc * 256 + ob,
                  (char*)Bs + o);
        }
        __syncthreads();
        #pragma unroll
        for (int ks = 0; ks < 4; ++ks) {
            const int kb = ks * 64 + l4 * 16;
            bf16x8 a[2], bb[4];
            #pragma unroll
            for (int fm = 0; fm < 2; ++fm) {
                const int row = wm * 32 + fm * 16 + l15;
                a[fm] = *(const bf16x8*)((const char*)As + row * 256 + (kb ^ ((row & 7) << 4)));
            }
            #pragma unroll
            for (int fn = 0; fn < 4; ++fn) {
                const int col = wn * 64 + fn * 16 + l15;
                bb[fn] = *(const bf16x8*)((const char*)Bs + col * 256 + (kb ^ ((col & 7) << 4)));
            }
            #pragma unroll
            for (int fm = 0; fm < 2; ++fm)
                #pragma unroll
                for (int fn = 0; fn < 4; ++fn)
                    acc[fm][fn] = __builtin_amdgcn_mfma_f32_16x16x32_bf16(
                        a[fm], bb[fn], acc[fm][fn], 0, 0, 0);
        }
        __syncthreads();
    }

    #pragma unroll
    for (int fm = 0; fm < 2; ++fm)
        #pragma unroll
        for (int fn = 0; fn < 4; ++fn) {
            const int col = wn * 64 + fn * 16 + l15;
            const float bv = bo[col];
            #pragma unroll
            for (int r = 0; r < 4; ++r) {
                const int row = rb * 64 + wm * 32 + fm * 16 + l4 * 4 + r;
                Out[(size_t)row * OUT_ + col] = acc[fm][fn][r] + bv;
            }
        }
}

// ---------------------------------------------------------------------------
extern "C" void kernel_launch(void* const* d_in, const int* in_sizes, int n_in,
                              void* d_out, int out_size, void* d_ws, size_t ws_size,
                              hipStream_t stream)
{
    const float* x     = (const float*)d_in[0];
    const int*   nidx  = (const int*)  d_in[1];
    const float* attr  = (const float*)d_in[2];
    const float* wq_w  = (const float*)d_in[3];
    const float* wq_b  = (const float*)d_in[4];
    const float* wk_w  = (const float*)d_in[5];
    const float* wk_b  = (const float*)d_in[6];
    const float* wv_w  = (const float*)d_in[7];
    const float* wv_b  = (const float*)d_in[8];
    const float* out_w = (const float*)d_in[9];
    const float* out_b = (const float*)d_in[10];
    float* out = (float*)d_out;

    char* ws = (char*)d_ws;
    size_t off = 0;
    auto alloc = [&](size_t bytes) -> char* {
        char* p = ws + off;
        off += (bytes + 255) & ~(size_t)255;
        return p;
    };
    u16*  Xbf  = (u16*)alloc((size_t)M_ * D_ * 2);          // 2MB
    u16*  Wbf  = (u16*)alloc((size_t)12 * D_ * D_ * 2);     // 384KB
    float* biasf = (float*)alloc((size_t)12 * D_ * 4);      // 6KB
    u16*  QKV  = (u16*)alloc((size_t)M_ * C3_ * 2);         // 24MB
    u16*  OWbf = (u16*)alloc((size_t)OUT_ * HD_ * 2);       // 128KB
    u16*  Obf  = (u16*)alloc((size_t)M_ * HD_ * 2);         // 8MB
    float* vsum = (float*)alloc((size_t)B_ * H_ * D_ * 4);  // 8KB
    int*  row_count = (int*)alloc((size_t)B_ * N_ * 4);
    int2* row_edges = (int2*)alloc((size_t)B_ * N_ * CAP * 8);

    prep_kernel<<<641, 256, 0, stream>>>(
        x, wq_w, wk_w, wv_w, wq_b, wk_b, wv_b, out_w,
        Xbf, Wbf, biasf, OWbf, row_count, vsum);
    append_kernel<<<(B_ * E_) / 32, 256, 0, stream>>>(nidx, attr, row_count, row_edges);
    qkv_mfma<<<64 * 12, 256, 0, stream>>>(Xbf, Wbf, biasf, QKV, vsum);
    row_fused<<<dim3(N_ / 4, B_), 256, 0, stream>>>(
        QKV, vsum, row_count, row_edges, Obf);
    out_mfma<<<M_ / 64, 256, 0, stream>>>(Obf, OWbf, out_b, out);
}

// Round 6
// 79.179 us; speedup vs baseline: 3.2725x; 1.0639x over previous
//
#include <hip/hip_runtime.h>
#include <hip/hip_bf16.h>
#include <math.h>

// Problem constants
constexpr int B_ = 4;
constexpr int N_ = 2048;
constexpr int D_ = 128;
constexpr int H_ = 4;
constexpr int E_ = 32768;
constexpr int W_ = 8;
constexpr int OUT_ = 128;
constexpr int HD_ = H_ * D_;    // 512
constexpr int C3_ = 3 * HD_;    // 1536 combined QKV cols
constexpr int CAP = 64;         // max edges per row bucket (Poisson(16))
constexpr int M_ = B_ * N_;     // 8192 rows

typedef __attribute__((ext_vector_type(8))) __bf16 bf16x8;
typedef __attribute__((ext_vector_type(4))) float f32x4;
typedef unsigned int uint32;
typedef unsigned short u16;

__device__ __forceinline__ u16 f2b(float f) {
    __hip_bfloat16 h = __float2bfloat16(f);
    return *(u16*)&h;
}
__device__ __forceinline__ float blo(uint32 u) { return __uint_as_float(u << 16); }
__device__ __forceinline__ float bhi(uint32 u) { return __uint_as_float(u & 0xffff0000u); }

// async 16B global->LDS copy (dest = wave-uniform base + lane*16)
__device__ __forceinline__ void g2l16(const void* g, void* l) {
    __builtin_amdgcn_global_load_lds(
        (const __attribute__((address_space(1))) unsigned int*)(uintptr_t)g,
        (__attribute__((address_space(3))) unsigned int*)(uintptr_t)l,
        16, 0, 0);
}

// ---------------------------------------------------------------------------
// prep_kernel: fused casts + zero(row_count, vsum).
// blocks [0,512): cast x -> Xbf (swizzled)
// blocks [512,608): cast 12 weight mats -> Wbf (swizzled) + bias copy
// blocks [608,640): cast out_w -> OWbf (swizzled)
// block 640: zero row_count (32KB) + vsum (8KB)
// ---------------------------------------------------------------------------
__global__ __launch_bounds__(256) void prep_kernel(
    const float* __restrict__ X,
    const float* __restrict__ wq, const float* __restrict__ wk, const float* __restrict__ wv,
    const float* __restrict__ bq, const float* __restrict__ bk, const float* __restrict__ bv,
    const float* __restrict__ OW,
    u16* __restrict__ Xbf, u16* __restrict__ Wbf, float* __restrict__ biasf,
    u16* __restrict__ OWbf,
    int* __restrict__ row_count, float* __restrict__ vsum)
{
    const int blk = blockIdx.x;
    if (blk < 512) {                       // ---- cast_x ----
        const int tid = blk * 256 + threadIdx.x;
        const int row = tid >> 4, sub = tid & 15;
        const float4 f0 = *(const float4*)(X + (size_t)row * 128 + sub * 8);
        const float4 f1 = *(const float4*)(X + (size_t)row * 128 + sub * 8 + 4);
        union { u16 u[8]; uint4 v; } pk;
        pk.u[0]=f2b(f0.x); pk.u[1]=f2b(f0.y); pk.u[2]=f2b(f0.z); pk.u[3]=f2b(f0.w);
        pk.u[4]=f2b(f1.x); pk.u[5]=f2b(f1.y); pk.u[6]=f2b(f1.z); pk.u[7]=f2b(f1.w);
        const int ob = row * 256 + ((sub * 16) ^ ((row & 7) << 4));
        *(uint4*)((char*)Xbf + ob) = pk.v;
    } else if (blk < 608) {                // ---- cast_w + bias ----
        const int c = (blk - 512) * 256 + threadIdx.x;   // 0..24575
        const int g = c >> 11, idx = c & 2047;
        const int t3 = g >> 2, h = g & 3;
        const float* Wsrc = (t3 == 0 ? wq : t3 == 1 ? wk : wv) + (size_t)h * 128 * 128;
        const int e = idx >> 4, sub = idx & 15;
        const float4 f0 = *(const float4*)(Wsrc + (size_t)e * 128 + sub * 8);
        const float4 f1 = *(const float4*)(Wsrc + (size_t)e * 128 + sub * 8 + 4);
        union { u16 u[8]; uint4 v; } pk;
        pk.u[0]=f2b(f0.x); pk.u[1]=f2b(f0.y); pk.u[2]=f2b(f0.z); pk.u[3]=f2b(f0.w);
        pk.u[4]=f2b(f1.x); pk.u[5]=f2b(f1.y); pk.u[6]=f2b(f1.z); pk.u[7]=f2b(f1.w);
        const int ob = g * 32768 + e * 256 + ((sub * 16) ^ ((e & 7) << 4));
        *(uint4*)((char*)Wbf + ob) = pk.v;
        if (idx < 128) {
            const float* Bsrc = (t3 == 0 ? bq : t3 == 1 ? bk : bv) + h * 128;
            biasf[g * 128 + idx] = Bsrc[idx];
        }
    } else if (blk < 640) {                // ---- cast_ow ----
        const int tid = (blk - 608) * 256 + threadIdx.x;  // 0..8191
        const int c = tid >> 6, sub = tid & 63;
        const float4 f0 = *(const float4*)(OW + (size_t)c * 512 + sub * 8);
        const float4 f1 = *(const float4*)(OW + (size_t)c * 512 + sub * 8 + 4);
        union { u16 u[8]; uint4 v; } pk;
        pk.u[0]=f2b(f0.x); pk.u[1]=f2b(f0.y); pk.u[2]=f2b(f0.z); pk.u[3]=f2b(f0.w);
        pk.u[4]=f2b(f1.x); pk.u[5]=f2b(f1.y); pk.u[6]=f2b(f1.z); pk.u[7]=f2b(f1.w);
        const int ob = c * 1024 + ((sub * 16) ^ ((c & 7) << 4));
        *(uint4*)((char*)OWbf + ob) = pk.v;
    } else {                               // ---- zero row_count + vsum ----
        const uint4 z = make_uint4(0, 0, 0, 0);
        uint4* rc = (uint4*)row_count;     // 2048 uint4 = 32KB
        #pragma unroll
        for (int q = 0; q < 8; ++q) rc[threadIdx.x + q * 256] = z;
        uint4* vs = (uint4*)vsum;          // 512 uint4 = 8KB
        #pragma unroll
        for (int q = 0; q < 2; ++q) vs[threadIdx.x + q * 256] = z;
    }
}

// ---------------------------------------------------------------------------
// qkv_append: fused QKV GEMM (blocks [0,768)) + edge append (blocks [768,1024)).
// qkv: QKV[8192][1536] bf16 = Xbf x Wbf^T + bias; V col-blocks also reduce vsum.
// append: 256 blocks x 4 waves x 16 iters x 8 edges = 131072 edges.
// ---------------------------------------------------------------------------
__global__ __launch_bounds__(256) void qkv_append(
    const u16* __restrict__ Xbf, const u16* __restrict__ Wbf,
    const float* __restrict__ biasf,
    const int* __restrict__ nidx, const float* __restrict__ attr,
    u16* __restrict__ QKV, float* __restrict__ vsum,
    int* __restrict__ row_count, int2* __restrict__ row_edges)
{
    __shared__ u16 As[128 * 128];
    __shared__ u16 Bs[128 * 128];
    const int t = threadIdx.x;
    const int lane = t & 63, wave = t >> 6;

    if (blockIdx.x >= 768) {               // ---- append path ----
        const int gw0 = (blockIdx.x - 768) * 4 + wave;   // 0..1023
        for (int it = 0; it < 16; ++it) {
            const int gw = gw0 + it * 1024;              // 0..16383
            const int e0g = gw * 8;
            const int b = e0g / E_;
            const int e0 = e0g % E_;
            float a = attr[((size_t)b * E_ + e0) * W_ + lane];
            a += __shfl_xor(a, 1);
            a += __shfl_xor(a, 2);
            a += __shfl_xor(a, 4);
            if ((lane & 7) == 0) {
                const int sub = lane >> 3;
                const int e = e0 + sub;
                const int i = nidx[b * 2 * E_ + e];
                const int j = nidx[b * 2 * E_ + E_ + e];
                const int pos = atomicAdd(&row_count[b * N_ + i], 1);
                if (pos < CAP)
                    row_edges[(size_t)(b * N_ + i) * CAP + pos] =
                        make_int2(e | (j << 16), __float_as_int(a));
            }
        }
        return;
    }

    // ---- qkv path ----
    const int rb = blockIdx.x & 63;
    const int g  = blockIdx.x >> 6;
    const int wm = wave >> 1, wn = wave & 1;
    const int l15 = lane & 15, l4 = lane >> 4;

    const char* Asrc = (const char*)(Xbf + (size_t)rb * 128 * 128);
    const char* Bsrc = (const char*)(Wbf + (size_t)g  * 128 * 128);
    #pragma unroll
    for (int q = 0; q < 8; ++q) {
        const int o = t * 16 + q * 4096;
        g2l16(Asrc + o, (char*)As + o);
        g2l16(Bsrc + o, (char*)Bs + o);
    }
    __syncthreads();

    f32x4 acc[4][4];
    #pragma unroll
    for (int i = 0; i < 4; ++i)
        #pragma unroll
        for (int j = 0; j < 4; ++j) acc[i][j] = (f32x4){0.f, 0.f, 0.f, 0.f};

    #pragma unroll
    for (int ks = 0; ks < 4; ++ks) {
        const int kb = ks * 64 + l4 * 16;
        bf16x8 a[4], bb[4];
        #pragma unroll
        for (int fm = 0; fm < 4; ++fm) {
            const int row = wm * 64 + fm * 16 + l15;
            a[fm] = *(const bf16x8*)((const char*)As + row * 256 + (kb ^ ((row & 7) << 4)));
        }
        #pragma unroll
        for (int fn = 0; fn < 4; ++fn) {
            const int col = wn * 64 + fn * 16 + l15;
            bb[fn] = *(const bf16x8*)((const char*)Bs + col * 256 + (kb ^ ((col & 7) << 4)));
        }
        #pragma unroll
        for (int fm = 0; fm < 4; ++fm)
            #pragma unroll
            for (int fn = 0; fn < 4; ++fn)
                acc[fm][fn] = __builtin_amdgcn_mfma_f32_16x16x32_bf16(
                    a[fm], bb[fn], acc[fm][fn], 0, 0, 0);
    }

    __syncthreads();   // all reads of As done; reuse As for C repack

    // write acc (+bias) into As as swizzled bf16 [row][256B]
    #pragma unroll
    for (int fm = 0; fm < 4; ++fm)
        #pragma unroll
        for (int fn = 0; fn < 4; ++fn) {
            const int col = wn * 64 + fn * 16 + l15;
            const float bv = biasf[g * 128 + col];
            #pragma unroll
            for (int r = 0; r < 4; ++r) {
                const int row = wm * 64 + fm * 16 + l4 * 4 + r;
                *(u16*)((char*)As + row * 256 + ((col * 2) ^ ((row & 7) << 4))) =
                    f2b(acc[fm][fn][r] + bv);
            }
        }

    if (g >= 8) {   // fused V column-sum (includes bias via +64*bv per wave)
        const int h = g - 8;
        const int b = rb >> 4;      // 16 row-blocks per batch
        #pragma unroll
        for (int fn = 0; fn < 4; ++fn) {
            float s = 0.f;
            #pragma unroll
            for (int fm = 0; fm < 4; ++fm)
                #pragma unroll
                for (int r = 0; r < 4; ++r) s += acc[fm][fn][r];
            s += __shfl_xor(s, 16);
            s += __shfl_xor(s, 32);
            if (l4 == 0) {
                const int col = wn * 64 + fn * 16 + l15;
                const float bv = biasf[g * 128 + col];
                atomicAdd(&vsum[(b * H_ + h) * 128 + col], s + 64.f * bv);
            }
        }
    }
    __syncthreads();

    // coalesced store: 8 x uint4 per thread
    #pragma unroll
    for (int q = 0; q < 8; ++q) {
        const int idx = t + q * 256;          // chunk 0..2047
        const int row = idx >> 4, c = idx & 15;
        const uint4 v = *(const uint4*)((char*)As + row * 256 + ((c * 16) ^ ((row & 7) << 4)));
        *(uint4*)(QKV + (size_t)(rb * 128 + row) * C3_ + g * 128 + c * 8) = v;
    }
}

// ---------------------------------------------------------------------------
// row_fused: wave-per-row scoring + sparse softmax + PV.
// Dual accumulator chains (2 edges per step) + pair prefetch: up to 8
// outstanding uint4 gathers per wave.
// grid = (N/4, B), block = 256 (4 independent waves, wave = row).
// ---------------------------------------------------------------------------
__global__ __launch_bounds__(256) void row_fused(
    const u16* __restrict__ QKV, const float* __restrict__ vsum,
    const int* __restrict__ row_count, const int2* __restrict__ row_edges,
    u16* __restrict__ Obf)
{
    const int t = threadIdx.x;
    const int wave = t >> 6, lane = t & 63;
    const int row = blockIdx.x * 4 + wave;
    const int b = blockIdx.y;
    const int R = b * N_ + row;
    int cnt = row_count[R];
    if (cnt > CAP) cnt = CAP;

    // edge entries register-resident: lane p < cnt holds entry p
    int ej = 0; float ws = 0.f;
    if (lane < cnt) {
        const int2 v = row_edges[(size_t)R * CAP + lane];
        ej = v.x; ws = __int_as_float(v.y);
    }
    // last-e-wins dedup via shfl broadcast (winner = max e per j)
    const int myj = ej >> 16, mye = ej & 0xFFFF;
    bool win = (lane < cnt);
    for (int p = 0; p < cnt; ++p) {
        const int oj = __shfl(ej, p);
        if (win && (oj >> 16) == myj && (oj & 0xFFFF) > mye) win = false;
    }
    unsigned long long m = __ballot(win);

    const char* base = (const char*)QKV;
    const uint4 qv = *(const uint4*)(base + (size_t)R * 3072 + lane * 16);
    const float q0=blo(qv.x), q1=bhi(qv.x), q2=blo(qv.y), q3=bhi(qv.y),
                q4=blo(qv.z), q5=bhi(qv.z), q6=blo(qv.w), q7=bhi(qv.w);
    const float rs = 0.02209708691207961f;   // 1/sqrt(2048)

    float A0=0.f,A1=0.f,A2=0.f,A3=0.f,A4=0.f,A5=0.f,A6=0.f,A7=0.f;
    float B0=0.f,B1=0.f,B2=0.f,B3=0.f,B4=0.f,B5=0.f,B6=0.f,B7=0.f;
    float dsA = 0.f, dsB = 0.f;

// fetch up to 2 edges from mask MM: loads kv/vv pairs, NN = count (1 or 2)
#define FETCH(MM, KV1,VV1,W1,KV2,VV2,W2,NN)                                  \
    { int p_ = (int)__ffsll((long long)MM) - 1; MM &= MM - 1;                \
      const int j_ = __shfl(ej, p_) >> 16; W1 = __shfl(ws, p_);              \
      const char* nb_ = base + (size_t)(b * N_ + j_) * 3072;                 \
      KV1 = *(const uint4*)(nb_ + 1024 + lane * 16);                         \
      VV1 = *(const uint4*)(nb_ + 2048 + lane * 16);                         \
      if (MM) {                                                              \
        int q_ = (int)__ffsll((long long)MM) - 1; MM &= MM - 1;              \
        const int j2_ = __shfl(ej, q_) >> 16; W2 = __shfl(ws, q_);           \
        const char* nb2_ = base + (size_t)(b * N_ + j2_) * 3072;             \
        KV2 = *(const uint4*)(nb2_ + 1024 + lane * 16);                      \
        VV2 = *(const uint4*)(nb2_ + 2048 + lane * 16);                      \
        NN = 2;                                                              \
      } else NN = 1; }

// process one edge into accumulator set S (A or B)
#define PROC(kv, vv, wsp, S)                                                 \
    { float s_ = q0*blo(kv.x) + q1*bhi(kv.x) + q2*blo(kv.y) + q3*bhi(kv.y)   \
               + q4*blo(kv.z) + q5*bhi(kv.z) + q6*blo(kv.w) + q7*bhi(kv.w);  \
      s_ += __shfl_xor(s_, 1);                                               \
      s_ += __shfl_xor(s_, 2);                                               \
      s_ += __shfl_xor(s_, 4);                                               \
      s_ += __shfl_xor(s_, 8);                                               \
      const float x_ = expf(s_ * rs * (wsp)) - 1.f;                          \
      ds##S += x_;                                                           \
      S##0 = fmaf(x_, blo(vv.x), S##0); S##1 = fmaf(x_, bhi(vv.x), S##1);    \
      S##2 = fmaf(x_, blo(vv.y), S##2); S##3 = fmaf(x_, bhi(vv.y), S##3);    \
      S##4 = fmaf(x_, blo(vv.z), S##4); S##5 = fmaf(x_, bhi(vv.z), S##5);    \
      S##6 = fmaf(x_, blo(vv.w), S##6); S##7 = fmaf(x_, bhi(vv.w), S##7); }

    if (m) {
        uint4 kv1, vv1, kv2, vv2; float w1, w2; int n1;
        FETCH(m, kv1, vv1, w1, kv2, vv2, w2, n1);
        while (m) {
            uint4 nk1, nv1, nk2, nv2; float nw1, nw2; int n2;
            FETCH(m, nk1, nv1, nw1, nk2, nv2, nw2, n2);
            PROC(kv1, vv1, w1, A);
            if (n1 == 2) PROC(kv2, vv2, w2, B);
            kv1 = nk1; vv1 = nv1; w1 = nw1;
            kv2 = nk2; vv2 = nv2; w2 = nw2; n1 = n2;
        }
        PROC(kv1, vv1, w1, A);
        if (n1 == 2) PROC(kv2, vv2, w2, B);
    }
#undef FETCH
#undef PROC

    const float inv = 1.0f / (2048.0f + dsA + dsB);
    const float* vsp = vsum + (b * H_ + (lane >> 4)) * 128 + (lane & 15) * 8;
    const float4 vs0 = *(const float4*)vsp;
    const float4 vs1 = *(const float4*)(vsp + 4);
    union { u16 u[8]; uint4 v; } o;
    o.u[0]=f2b((vs0.x+A0+B0)*inv); o.u[1]=f2b((vs0.y+A1+B1)*inv);
    o.u[2]=f2b((vs0.z+A2+B2)*inv); o.u[3]=f2b((vs0.w+A3+B3)*inv);
    o.u[4]=f2b((vs1.x+A4+B4)*inv); o.u[5]=f2b((vs1.y+A5+B5)*inv);
    o.u[6]=f2b((vs1.z+A6+B6)*inv); o.u[7]=f2b((vs1.w+A7+B7)*inv);
    const int ob = ((lane >> 4) << 8) + (((lane & 15) * 16) ^ ((R & 7) << 4));
    *(uint4*)((char*)Obf + (size_t)R * 1024 + ob) = o.v;
}

// ---------------------------------------------------------------------------
// out_mfma: d_out[8192][128] f32 = Obf[8192][512] x OWbf[128][512]^T + out_b
// grid = 256 row-blocks (M-tile 32), 4 waves (2x2), wave tile 16x64.
// ---------------------------------------------------------------------------
__global__ __launch_bounds__(256) void out_mfma(
    const u16* __restrict__ Obf, const u16* __restrict__ OWbf,
    const float* __restrict__ bo, float* __restrict__ Out)
{
    __shared__ u16 As[32 * 128];    // 8KB
    __shared__ u16 Bs[128 * 128];   // 32KB
    const int rb = blockIdx.x;
    const int t = threadIdx.x;
    const int lane = t & 63, wave = t >> 6;
    const int wm = wave >> 1, wn = wave & 1;
    const int l15 = lane & 15, l4 = lane >> 4;

    f32x4 acc[4];
    #pragma unroll
    for (int j = 0; j < 4; ++j) acc[j] = (f32x4){0.f, 0.f, 0.f, 0.f};

    for (int kc = 0; kc < 4; ++kc) {
        #pragma unroll
        for (int q = 0; q < 2; ++q) {       // A: 8KB
            const int o = t * 16 + q * 4096;
            const int arow = o >> 8, ob = o & 255;
            g2l16((const char*)Obf + (size_t)(rb * 32 + arow) * 1024 + kc * 256 + ob,
                  (char*)As + o);
        }
        #pragma unroll
        for (int q = 0; q < 8; ++q) {       // B: 32KB
            const int o = t * 16 + q * 4096;
            const int c = o >> 8, ob = o & 255;
            g2l16((const char*)OWbf + (size_t)c * 1024 + kc * 256 + ob,
                  (char*)Bs + o);
        }
        __syncthreads();
        #pragma unroll
        for (int ks = 0; ks < 4; ++ks) {
            const int kb = ks * 64 + l4 * 16;
            bf16x8 a0, bb[4];
            {
                const int row = wm * 16 + l15;
                a0 = *(const bf16x8*)((const char*)As + row * 256 + (kb ^ ((row & 7) << 4)));
            }
            #pragma unroll
            for (int fn = 0; fn < 4; ++fn) {
                const int col = wn * 64 + fn * 16 + l15;
                bb[fn] = *(const bf16x8*)((const char*)Bs + col * 256 + (kb ^ ((col & 7) << 4)));
            }
            #pragma unroll
            for (int fn = 0; fn < 4; ++fn)
                acc[fn] = __builtin_amdgcn_mfma_f32_16x16x32_bf16(
                    a0, bb[fn], acc[fn], 0, 0, 0);
        }
        __syncthreads();
    }

    #pragma unroll
    for (int fn = 0; fn < 4; ++fn) {
        const int col = wn * 64 + fn * 16 + l15;
        const float bv = bo[col];
        #pragma unroll
        for (int r = 0; r < 4; ++r) {
            const int row = rb * 32 + wm * 16 + l4 * 4 + r;
            Out[(size_t)row * OUT_ + col] = acc[fn][r] + bv;
        }
    }
}

// ---------------------------------------------------------------------------
extern "C" void kernel_launch(void* const* d_in, const int* in_sizes, int n_in,
                              void* d_out, int out_size, void* d_ws, size_t ws_size,
                              hipStream_t stream)
{
    const float* x     = (const float*)d_in[0];
    const int*   nidx  = (const int*)  d_in[1];
    const float* attr  = (const float*)d_in[2];
    const float* wq_w  = (const float*)d_in[3];
    const float* wq_b  = (const float*)d_in[4];
    const float* wk_w  = (const float*)d_in[5];
    const float* wk_b  = (const float*)d_in[6];
    const float* wv_w  = (const float*)d_in[7];
    const float* wv_b  = (const float*)d_in[8];
    const float* out_w = (const float*)d_in[9];
    const float* out_b = (const float*)d_in[10];
    float* out = (float*)d_out;

    char* ws = (char*)d_ws;
    size_t off = 0;
    auto alloc = [&](size_t bytes) -> char* {
        char* p = ws + off;
        off += (bytes + 255) & ~(size_t)255;
        return p;
    };
    u16*  Xbf  = (u16*)alloc((size_t)M_ * D_ * 2);          // 2MB
    u16*  Wbf  = (u16*)alloc((size_t)12 * D_ * D_ * 2);     // 384KB
    float* biasf = (float*)alloc((size_t)12 * D_ * 4);      // 6KB
    u16*  QKV  = (u16*)alloc((size_t)M_ * C3_ * 2);         // 24MB
    u16*  OWbf = (u16*)alloc((size_t)OUT_ * HD_ * 2);       // 128KB
    u16*  Obf  = (u16*)alloc((size_t)M_ * HD_ * 2);         // 8MB
    float* vsum = (float*)alloc((size_t)B_ * H_ * D_ * 4);  // 8KB
    int*  row_count = (int*)alloc((size_t)B_ * N_ * 4);
    int2* row_edges = (int2*)alloc((size_t)B_ * N_ * CAP * 8);

    prep_kernel<<<641, 256, 0, stream>>>(
        x, wq_w, wk_w, wv_w, wq_b, wk_b, wv_b, out_w,
        Xbf, Wbf, biasf, OWbf, row_count, vsum);
    qkv_append<<<1024, 256, 0, stream>>>(
        Xbf, Wbf, biasf, nidx, attr, QKV, vsum, row_count, row_edges);
    row_fused<<<dim3(N_ / 4, B_), 256, 0, stream>>>(
        QKV, vsum, row_count, row_edges, Obf);
    out_mfma<<<M_ / 32, 256, 0, stream>>>(Obf, OWbf, out_b, out);
}